// Round 4
// baseline (2383.211 us; speedup 1.0000x reference)
//
#include <hip/hip_runtime.h>
#include <cstdint>
#include <cstddef>

typedef __bf16 bf16_t;
typedef __bf16 bf16x8 __attribute__((ext_vector_type(8)));
typedef float f32x4 __attribute__((ext_vector_type(4)));
typedef int i32x4 __attribute__((ext_vector_type(4)));

#define B_ 4
#define T_ 1024
#define C_ 1024
#define H_ 16
#define L_ 6
#define V_ 32000
#define M_ (B_ * T_)   // 4096

// ---------------------------------------------------------------- embedding
__global__ __launch_bounds__(256) void k_embed(const int* __restrict__ idx,
                                               const float* __restrict__ tok,
                                               const float* __restrict__ pos,
                                               float* __restrict__ x) {
  int row = blockIdx.x;            // b*T + t
  int t = row & (T_ - 1);
  int id = idx[row];
  int c = threadIdx.x * 4;
  f32x4 a = *(const f32x4*)(tok + (size_t)id * C_ + c);
  f32x4 p = *(const f32x4*)(pos + (size_t)t * C_ + c);
  *(f32x4*)(x + (size_t)row * C_ + c) = a + p;
}

// ---------------------------------------------------------------- layernorm (f32 in -> bf16 out)
__global__ __launch_bounds__(256) void k_ln(const float* __restrict__ x,
                                            const float* __restrict__ w,
                                            const float* __restrict__ b,
                                            bf16_t* __restrict__ out) {
  __shared__ float red[8];
  int row = blockIdx.x;
  int tid = threadIdx.x;
  const float* xr = x + (size_t)row * C_;
  f32x4 v = *(const f32x4*)(xr + tid * 4);
  float s = v[0] + v[1] + v[2] + v[3];
  float q = v[0] * v[0] + v[1] * v[1] + v[2] * v[2] + v[3] * v[3];
#pragma unroll
  for (int off = 32; off; off >>= 1) {
    s += __shfl_xor(s, off);
    q += __shfl_xor(q, off);
  }
  int wid = tid >> 6;
  if ((tid & 63) == 0) { red[wid * 2] = s; red[wid * 2 + 1] = q; }
  __syncthreads();
  s = red[0] + red[2] + red[4] + red[6];
  q = red[1] + red[3] + red[5] + red[7];
  float mu = s * (1.f / C_);
  float var = q * (1.f / C_) - mu * mu;
  float rstd = rsqrtf(var + 1e-5f);
  f32x4 wv = *(const f32x4*)(w + tid * 4);
  f32x4 bv = *(const f32x4*)(b + tid * 4);
  bf16_t* o = out + (size_t)row * C_ + tid * 4;
#pragma unroll
  for (int j = 0; j < 4; j++) o[j] = (bf16_t)((v[j] - mu) * rstd * wv[j] + bv[j]);
}

// ------------------------------------------------- f32 [K][N] -> bf16 [N][K] transpose
__global__ __launch_bounds__(256) void k_transpose_bf16(const float* __restrict__ in,
                                                        bf16_t* __restrict__ out,
                                                        int K, int N) {
  __shared__ float tile[32][33];
  int n0 = blockIdx.x * 32, k0 = blockIdx.y * 32;
  int tid = threadIdx.x;
  int cr = tid >> 5, cc = tid & 31;
#pragma unroll
  for (int it = 0; it < 4; it++) {
    int r = it * 8 + cr;
    tile[r][cc] = in[(size_t)(k0 + r) * N + n0 + cc];
  }
  __syncthreads();
#pragma unroll
  for (int it = 0; it < 4; it++) {
    int r = it * 8 + cr;                       // local n
    out[(size_t)(n0 + r) * K + k0 + cc] = (bf16_t)tile[cc][r];
  }
}

// ------------------------------------------------- split qkv -> q (scaled), k in [B][H][T][D]
__global__ __launch_bounds__(256) void k_reshape_qk(const bf16_t* __restrict__ qkv,
                                                    bf16_t* __restrict__ qh,
                                                    bf16_t* __restrict__ kh) {
  int g = blockIdx.x * 256 + threadIdx.x;      // ((b*H+h)*T + t)*64 + d
  int d = g & 63;
  int t = (g >> 6) & (T_ - 1);
  int h = (g >> 16) & (H_ - 1);
  int b = g >> 20;
  size_t src = ((size_t)(b * T_ + t)) * (3 * C_) + h * 64 + d;
  qh[g] = (bf16_t)((float)qkv[src] * 0.125f);  // 1/sqrt(64), exact pow2
  kh[g] = qkv[src + C_];
}

// ------------------------------------------------- v -> vT [B][H][D][T]
__global__ __launch_bounds__(256) void k_vtrans(const bf16_t* __restrict__ qkv,
                                                bf16_t* __restrict__ vT) {
  __shared__ bf16_t tile[64][65];
  int bh = blockIdx.x;
  int t0 = blockIdx.y * 64;
  int tid = threadIdx.x;
  int c = tid & 63, rr = tid >> 6;
  int b = bh >> 4, h = bh & (H_ - 1);
  const bf16_t* src = qkv + ((size_t)(b * T_ + t0)) * (3 * C_) + 2 * C_ + h * 64;
#pragma unroll
  for (int it = 0; it < 16; it++) {
    int r = it * 4 + rr;
    tile[r][c] = src[(size_t)r * (3 * C_) + c];
  }
  __syncthreads();
  bf16_t* dst = vT + (size_t)bh * 64 * T_ + t0;
#pragma unroll
  for (int it = 0; it < 16; it++) {
    int dr = it * 4 + rr;                      // d
    dst[(size_t)dr * T_ + c] = tile[c][dr];
  }
}

// ---------------------------------------------------------------- flash attention
__global__ __launch_bounds__(256) void k_attn(const bf16_t* __restrict__ qh,
                                              const bf16_t* __restrict__ kh,
                                              const bf16_t* __restrict__ vT,
                                              bf16_t* __restrict__ outb) {
  __shared__ bf16_t p_lds[4][16 * 32];
  int tid = threadIdx.x, lane = tid & 63, wid = tid >> 6;
  int bh = blockIdx.x;
  int b = bh >> 4, h = bh & (H_ - 1);
  int qbase = blockIdx.y * 64 + wid * 16;
  const bf16_t* qp = qh + ((size_t)bh * T_ + qbase) * 64;
  const bf16_t* kp = kh + (size_t)bh * T_ * 64;
  const bf16_t* vp = vT + (size_t)bh * 64 * T_;
  int r = lane & 15, g = lane >> 4;

  bf16x8 qf0 = *(const bf16x8*)(qp + r * 64 + g * 8);
  bf16x8 qf1 = *(const bf16x8*)(qp + r * 64 + 32 + g * 8);

  f32x4 o[4];
  float m[4], l[4];
#pragma unroll
  for (int j = 0; j < 4; j++) { m[j] = -1e30f; l[j] = 0.f; o[j] = (f32x4){0.f, 0.f, 0.f, 0.f}; }

  int kv_end = qbase + 16;
  for (int jb = 0; jb < kv_end; jb += 32) {
    f32x4 s0 = (f32x4){0.f, 0.f, 0.f, 0.f};
    f32x4 s1 = (f32x4){0.f, 0.f, 0.f, 0.f};
    const bf16_t* kb0 = kp + (size_t)(jb + r) * 64 + g * 8;
    const bf16_t* kb1 = kb0 + 16 * 64;
    s0 = __builtin_amdgcn_mfma_f32_16x16x32_bf16(qf0, *(const bf16x8*)(kb0), s0, 0, 0, 0);
    s0 = __builtin_amdgcn_mfma_f32_16x16x32_bf16(qf1, *(const bf16x8*)(kb0 + 32), s0, 0, 0, 0);
    s1 = __builtin_amdgcn_mfma_f32_16x16x32_bf16(qf0, *(const bf16x8*)(kb1), s1, 0, 0, 0);
    s1 = __builtin_amdgcn_mfma_f32_16x16x32_bf16(qf1, *(const bf16x8*)(kb1 + 32), s1, 0, 0, 0);

    float p0[4], p1[4], fac[4];
#pragma unroll
    for (int j = 0; j < 4; j++) {
      int rowg = qbase + g * 4 + j;
      float v0 = s0[j], v1 = s1[j];
      if (jb + r > rowg) v0 = -1e30f;
      if (jb + 16 + r > rowg) v1 = -1e30f;
      float t = fmaxf(v0, v1);
      t = fmaxf(t, __shfl_xor(t, 1));
      t = fmaxf(t, __shfl_xor(t, 2));
      t = fmaxf(t, __shfl_xor(t, 4));
      t = fmaxf(t, __shfl_xor(t, 8));
      float nm = fmaxf(m[j], t);
      p0[j] = __expf(v0 - nm);
      p1[j] = __expf(v1 - nm);
      float f = __expf(m[j] - nm);
      float ts = p0[j] + p1[j];
      ts += __shfl_xor(ts, 1);
      ts += __shfl_xor(ts, 2);
      ts += __shfl_xor(ts, 4);
      ts += __shfl_xor(ts, 8);
      l[j] = l[j] * f + ts;
      m[j] = nm;
      fac[j] = f;
    }
    f32x4 fv = (f32x4){fac[0], fac[1], fac[2], fac[3]};
#pragma unroll
    for (int d = 0; d < 4; d++) o[d] *= fv;

    bf16_t* pl = p_lds[wid];
#pragma unroll
    for (int j = 0; j < 4; j++) {
      pl[(g * 4 + j) * 32 + r] = (bf16_t)p0[j];
      pl[(g * 4 + j) * 32 + 16 + r] = (bf16_t)p1[j];
    }
    bf16x8 pa = *(const bf16x8*)(pl + r * 32 + g * 8);
#pragma unroll
    for (int d = 0; d < 4; d++) {
      const bf16_t* vf = vp + (size_t)(d * 16 + r) * T_ + jb + g * 8;
      o[d] = __builtin_amdgcn_mfma_f32_16x16x32_bf16(pa, *(const bf16x8*)(vf), o[d], 0, 0, 0);
    }
  }

#pragma unroll
  for (int d = 0; d < 4; d++) {
#pragma unroll
    for (int j = 0; j < 4; j++) {
      float val = o[d][j] / l[j];
      outb[((size_t)(b * T_ + qbase + g * 4 + j)) * C_ + h * 64 + d * 16 + r] = (bf16_t)val;
    }
  }
}

// ---------------------------------------------------------------- shared helpers
__device__ __forceinline__ void gld_lds16(const bf16_t* g, bf16_t* l) {
  __builtin_amdgcn_global_load_lds((const __attribute__((address_space(1))) void*)g,
                                   (__attribute__((address_space(3))) void*)l, 16, 0, 0);
}
__device__ __forceinline__ bf16x8 lds_rd128(uint32_t addr) {
  i32x4 d;
  asm volatile("ds_read_b128 %0, %1" : "=v"(d) : "v"(addr));
  return __builtin_bit_cast(bf16x8, d);
}
#define BAR_() __builtin_amdgcn_s_barrier()
#define SCHED0_() __builtin_amdgcn_sched_barrier(0)
#define WLG0_() do { asm volatile("s_waitcnt lgkmcnt(0)" ::: "memory"); SCHED0_(); } while (0)

// ---------------------------------------------------------------- 128x128 2-phase GEMM (small grids)
template <int OUTBF, int HASB, int HASRELU, int HASRES>
__global__ __launch_bounds__(256) void k_gemm(const bf16_t* __restrict__ A,
                                              const bf16_t* __restrict__ Bt,
                                              const float* __restrict__ bias,
                                              const float* resid,
                                              void* Cout, int M, int N, int K) {
  __shared__ bf16_t As[2][128 * 32];
  __shared__ bf16_t Bs[2][128 * 32];
  int tid = threadIdx.x;
  int lane = tid & 63, wid = tid >> 6;
  size_t rowBase = (size_t)blockIdx.y * 128;
  size_t colBase = (size_t)blockIdx.x * 128;

  const bf16_t* gA = A + (rowBase + (tid >> 2)) * (size_t)K + (tid & 3) * 8;
  const bf16_t* gB = Bt + (colBase + (tid >> 2)) * (size_t)K + (tid & 3) * 8;
  const size_t gStep64 = (size_t)64 * K;

  f32x4 acc[4][4];
#pragma unroll
  for (int i = 0; i < 4; i++)
#pragma unroll
    for (int j = 0; j < 4; j++) acc[i][j] = (f32x4){0.f, 0.f, 0.f, 0.f};

  int NK = K >> 5;
  {
    bf16_t* la = &As[0][0] + wid * 512;
    bf16_t* lb = &Bs[0][0] + wid * 512;
    gld_lds16(gA, la);            gld_lds16(gA + gStep64, la + 2048);
    gld_lds16(gB, lb);            gld_lds16(gB + gStep64, lb + 2048);
  }

  int wr = (wid >> 1) * 64, wc = (wid & 1) * 64;
  int r15 = lane & 15, g4 = lane >> 4;

  for (int kt = 0; kt < NK; kt++) {
    int buf = kt & 1;
    __syncthreads();
    if (kt + 1 < NK) {
      const bf16_t* ga = gA + (size_t)(kt + 1) * 32;
      const bf16_t* gb = gB + (size_t)(kt + 1) * 32;
      bf16_t* la = &As[buf ^ 1][0] + wid * 512;
      bf16_t* lb = &Bs[buf ^ 1][0] + wid * 512;
      gld_lds16(ga, la);          gld_lds16(ga + gStep64, la + 2048);
      gld_lds16(gb, lb);          gld_lds16(gb + gStep64, lb + 2048);
    }
    const bf16_t* as = &As[buf][0] + (wr + r15) * 32 + g4 * 8;
    const bf16_t* bs = &Bs[buf][0] + (wc + r15) * 32 + g4 * 8;
    bf16x8 af[4], bfr[4];
#pragma unroll
    for (int i = 0; i < 4; i++) af[i] = *(const bf16x8*)(as + i * 16 * 32);
#pragma unroll
    for (int i = 0; i < 4; i++) bfr[i] = *(const bf16x8*)(bs + i * 16 * 32);
#pragma unroll
    for (int i = 0; i < 4; i++)
#pragma unroll
      for (int j = 0; j < 4; j++)
        acc[i][j] = __builtin_amdgcn_mfma_f32_16x16x32_bf16(af[i], bfr[j], acc[i][j], 0, 0, 0);
  }

#pragma unroll
  for (int i = 0; i < 4; i++) {
    size_t row0 = rowBase + wr + i * 16 + g4 * 4;
#pragma unroll
    for (int j = 0; j < 4; j++) {
      size_t col = colBase + wc + j * 16 + r15;
      float bi = HASB ? bias[col] : 0.f;
#pragma unroll
      for (int q = 0; q < 4; q++) {
        size_t row = row0 + q;
        float v = acc[i][j][q] + bi;
        if (HASRELU) v = fmaxf(v, 0.f);
        if (HASRES) v += resid[row * (size_t)N + col];
        if (OUTBF)
          ((bf16_t*)Cout)[row * (size_t)N + col] = (bf16_t)v;
        else
          ((float*)Cout)[row * (size_t)N + col] = v;
      }
    }
  }
}

// ---------------------------------------------------------------- 256x256 8-phase GEMM
// BM=BN=256, BK=64, 8 waves (2Mx4N), per-wave 128x64 out.
// T2 swizzle (3-bit): physical_byte = row*128 + (intra ^ ((row&7)<<4)).
// Deep prefetch: ALL 8 stage loads for tile kt+1 issue at phase 0 of iter kt;
// vmcnt(8) drains tile kt's loads (issued a full iteration = 4 phases earlier).
#define STAGE_(q, tk, bufv)                                                           \
  do {                                                                                \
    const bf16_t* _ga = A + (size_t)(rowBase + (q)*64 + srow) * (size_t)K +           \
                        (size_t)(tk)*64 + scol;                                       \
    const bf16_t* _gb = Bt + (size_t)(colBase + (q)*64 + srow) * (size_t)K +          \
                        (size_t)(tk)*64 + scol;                                       \
    gld_lds16(_ga, AsF + (bufv)*16384 + (q)*4096 + w * 512);                          \
    gld_lds16(_gb, BsF + (bufv)*16384 + (q)*4096 + w * 512);                          \
  } while (0)

#define LDA_(mh, bufv)                                                                \
  do {                                                                                \
    uint32_t _ab = aRd + (uint32_t)(bufv)*32768u + (mh)*8192u;                        \
    _Pragma("unroll") for (int _m = 0; _m < 4; _m++)                                  \
        _Pragma("unroll") for (int _k = 0; _k < 2; _k++)                              \
            af[_m][_k] = lds_rd128(_ab + _m * 2048 + (_k ? offK1 : offK0));           \
  } while (0)

#define LDB_(nh, bufv)                                                                \
  do {                                                                                \
    uint32_t _bb = bRd + (uint32_t)(bufv)*32768u + (nh)*4096u;                        \
    _Pragma("unroll") for (int _n = 0; _n < 2; _n++)                                  \
        _Pragma("unroll") for (int _k = 0; _k < 2; _k++)                              \
            bfr[_n][_k] = lds_rd128(_bb + _n * 2048 + (_k ? offK1 : offK0));          \
  } while (0)

#define MFQ_(mh, nh)                                                                  \
  do {                                                                                \
    __builtin_amdgcn_s_setprio(1);                                                    \
    _Pragma("unroll") for (int _m = 0; _m < 4; _m++)                                  \
        _Pragma("unroll") for (int _n = 0; _n < 2; _n++)                              \
            _Pragma("unroll") for (int _k = 0; _k < 2; _k++)                          \
                acc[(mh)*4 + _m][(nh)*2 + _n] = __builtin_amdgcn_mfma_f32_16x16x32_bf16( \
                    af[_m][_k], bfr[_n][_k], acc[(mh)*4 + _m][(nh)*2 + _n], 0, 0, 0); \
    __builtin_amdgcn_s_setprio(0);                                                    \
  } while (0)

template <int OUTBF, int HASB, int HASRELU, int HASRES>
__global__ __launch_bounds__(512, 2) void k_gemm256(const bf16_t* __restrict__ A,
                                                    const bf16_t* __restrict__ Bt,
                                                    const float* __restrict__ bias,
                                                    const float* resid,
                                                    void* Cout, int M, int N, int K) {
  __shared__ bf16_t As[2][256][64];
  __shared__ bf16_t Bs[2][256][64];
  bf16_t* AsF = &As[0][0][0];
  bf16_t* BsF = &Bs[0][0][0];
  const uint32_t asb = (uint32_t)(uintptr_t)AsF;
  const uint32_t bsb = (uint32_t)(uintptr_t)BsF;

  int tid = threadIdx.x, lane = tid & 63, w = tid >> 6;
  int wr = w >> 2, wc = w & 3;
  int r15 = lane & 15, g4 = lane >> 4;

  // XCD-bijective swizzle, column-major decomposition (consecutive -> same B panel)
  int nwg = (int)gridDim.x;
  int bid = (int)blockIdx.x;
  int xcd = bid & 7, loc = bid >> 3;
  int q8 = nwg >> 3, r8 = nwg & 7;
  int swz = (xcd < r8) ? xcd * (q8 + 1) + loc : r8 * (q8 + 1) + (xcd - r8) * q8 + loc;
  int nY = M >> 8;
  int by = swz % nY, bx = swz / nY;
  int rowBase = by * 256, colBase = bx * 256;

  // stage source: linear LDS dest (lane -> row w*8+(lane>>3), byte col (lane&7)*16)
  // holds logical col ((lane&7) ^ (lane>>3)) * 8 elements  (inverse of 3-bit XOR)
  int srow = w * 8 + (lane >> 3);
  int scol = ((lane & 7) ^ (lane >> 3)) * 8;

  // read-side: row-base (no XOR) + intra-row offset XOR'd with (row&7)<<4
  uint32_t xm = (uint32_t)((r15 & 7) << 4);
  uint32_t offK0 = ((uint32_t)(g4 * 16)) ^ xm;
  uint32_t offK1 = ((uint32_t)(g4 * 16 + 64)) ^ xm;
  uint32_t aRd = asb + (uint32_t)((wr * 128 + r15) * 128);
  uint32_t bRd = bsb + (uint32_t)((wc * 64 + r15) * 128);

  f32x4 acc[8][4];
#pragma unroll
  for (int i = 0; i < 8; i++)
#pragma unroll
    for (int j = 0; j < 4; j++) acc[i][j] = (f32x4){0.f, 0.f, 0.f, 0.f};

  bf16x8 af[4][2], bfr[2][2];

#pragma unroll
  for (int q = 0; q < 4; q++) STAGE_(q, 0, 0);

  int NT = K >> 6;
  for (int kt = 0; kt < NT; ++kt) {
    int buf = kt & 1;
    bool pf = (kt + 1 < NT);
    // ---- phase 0: issue ALL next-tile stages, counted wait on current tile.
    // buf^1's last reads drained before the end-of-iter barrier, so the
    // overwrite is safe; tile kt's loads have had 4 phases to land.
    if (pf) {
#pragma unroll
      for (int q = 0; q < 4; q++) STAGE_(q, kt + 1, buf ^ 1);
      asm volatile("s_waitcnt vmcnt(8)" ::: "memory");
    } else {
      asm volatile("s_waitcnt vmcnt(0)" ::: "memory");
    }
    BAR_();
    SCHED0_();
    LDA_(0, buf);
    LDB_(0, buf);
    WLG0_();
    MFQ_(0, 0);
    BAR_();
    // ---- phase 1
    LDB_(1, buf);
    BAR_();
    WLG0_();
    MFQ_(0, 1);
    BAR_();
    // ---- phase 2
    LDA_(1, buf);
    BAR_();
    WLG0_();
    MFQ_(1, 1);
    BAR_();
    // ---- phase 3
    LDB_(0, buf);
    BAR_();
    WLG0_();
    MFQ_(1, 0);
    BAR_();
  }

#pragma unroll
  for (int m = 0; m < 8; m++) {
    size_t row0 = (size_t)rowBase + wr * 128 + m * 16 + g4 * 4;
#pragma unroll
    for (int n = 0; n < 4; n++) {
      size_t col = (size_t)colBase + wc * 64 + n * 16 + r15;
      float bi = HASB ? bias[col] : 0.f;
#pragma unroll
      for (int qq = 0; qq < 4; qq++) {
        size_t row = row0 + qq;
        float v = acc[m][n][qq] + bi;
        if (HASRELU) v = fmaxf(v, 0.f);
        if (HASRES) v += resid[row * (size_t)N + col];
        if (OUTBF)
          ((bf16_t*)Cout)[row * (size_t)N + col] = (bf16_t)v;
        else
          ((float*)Cout)[row * (size_t)N + col] = v;
      }
    }
  }
}

// ---------------------------------------------------------------- launch
extern "C" void kernel_launch(void* const* d_in, const int* in_sizes, int n_in,
                              void* d_out, int out_size, void* d_ws, size_t ws_size,
                              hipStream_t stream) {
  (void)in_sizes; (void)n_in; (void)out_size; (void)ws_size;
  const int* idx = (const int*)d_in[0];
  const float* tok_emb = (const float*)d_in[1];
  const float* pos_emb = (const float*)d_in[2];
  const float* qkv_w = (const float*)d_in[3];
  const float* attn_out_w = (const float*)d_in[4];
  const float* attn_out_b = (const float*)d_in[5];
  const float* fc1_w = (const float*)d_in[6];
  const float* fc1_b = (const float*)d_in[7];
  const float* fc2_w = (const float*)d_in[8];
  const float* fc2_b = (const float*)d_in[9];
  const float* ln1_w = (const float*)d_in[10];
  const float* ln1_b = (const float*)d_in[11];
  const float* ln2_w = (const float*)d_in[12];
  const float* ln2_b = (const float*)d_in[13];
  const float* lnf_w = (const float*)d_in[14];
  const float* lnf_b = (const float*)d_in[15];
  const float* head_w = (const float*)d_in[16];
  float* out = (float*)d_out;

  char* wsp = (char*)d_ws;
  auto alloc = [&](size_t bytes) {
    char* p = wsp;
    wsp += (bytes + 255) & ~(size_t)255;
    return p;
  };
  float* x      = (float*)alloc((size_t)M_ * C_ * 4);
  bf16_t* hbuf  = (bf16_t*)alloc((size_t)M_ * C_ * 2);
  bf16_t* qkvb  = (bf16_t*)alloc((size_t)M_ * 3 * C_ * 2);
  bf16_t* qhb   = (bf16_t*)alloc((size_t)M_ * C_ * 2);
  bf16_t* khb   = (bf16_t*)alloc((size_t)M_ * C_ * 2);
  bf16_t* vTb   = (bf16_t*)alloc((size_t)M_ * C_ * 2);
  bf16_t* attnb = (bf16_t*)alloc((size_t)M_ * C_ * 2);
  bf16_t* midb  = (bf16_t*)alloc((size_t)M_ * 4 * C_ * 2);
  bf16_t* qkvwT = (bf16_t*)alloc((size_t)3 * C_ * C_ * 2);
  bf16_t* owT   = (bf16_t*)alloc((size_t)C_ * C_ * 2);
  bf16_t* fc1wT = (bf16_t*)alloc((size_t)4 * C_ * C_ * 2);
  bf16_t* fc2wT = (bf16_t*)alloc((size_t)4 * C_ * C_ * 2);
  bf16_t* headwT= (bf16_t*)alloc((size_t)C_ * V_ * 2);

  k_embed<<<M_, 256, 0, stream>>>(idx, tok_emb, pos_emb, x);
  k_transpose_bf16<<<dim3(V_ / 32, C_ / 32), 256, 0, stream>>>(head_w, headwT, C_, V_);

  for (int l = 0; l < L_; l++) {
    k_transpose_bf16<<<dim3(3 * C_ / 32, C_ / 32), 256, 0, stream>>>(
        qkv_w + (size_t)l * C_ * 3 * C_, qkvwT, C_, 3 * C_);
    k_transpose_bf16<<<dim3(C_ / 32, C_ / 32), 256, 0, stream>>>(
        attn_out_w + (size_t)l * C_ * C_, owT, C_, C_);
    k_transpose_bf16<<<dim3(4 * C_ / 32, C_ / 32), 256, 0, stream>>>(
        fc1_w + (size_t)l * C_ * 4 * C_, fc1wT, C_, 4 * C_);
    k_transpose_bf16<<<dim3(C_ / 32, 4 * C_ / 32), 256, 0, stream>>>(
        fc2_w + (size_t)l * 4 * C_ * C_, fc2wT, 4 * C_, C_);

    k_ln<<<M_, 256, 0, stream>>>(x, ln1_w + l * C_, ln1_b + l * C_, hbuf);
    k_gemm256<1, 0, 0, 0><<<dim3((3 * C_ / 256) * (M_ / 256)), 512, 0, stream>>>(
        hbuf, qkvwT, nullptr, nullptr, qkvb, M_, 3 * C_, C_);
    k_reshape_qk<<<(M_ * C_) / 256, 256, 0, stream>>>(qkvb, qhb, khb);
    k_vtrans<<<dim3(B_ * H_, T_ / 64), 256, 0, stream>>>(qkvb, vTb);
    k_attn<<<dim3(B_ * H_, T_ / 64), 256, 0, stream>>>(qhb, khb, vTb, attnb);
    k_gemm<0, 1, 0, 1><<<dim3(C_ / 128, M_ / 128), 256, 0, stream>>>(
        attnb, owT, attn_out_b + l * C_, x, x, M_, C_, C_);

    k_ln<<<M_, 256, 0, stream>>>(x, ln2_w + l * C_, ln2_b + l * C_, hbuf);
    k_gemm256<1, 1, 1, 0><<<dim3((4 * C_ / 256) * (M_ / 256)), 512, 0, stream>>>(
        hbuf, fc1wT, fc1_b + (size_t)l * 4 * C_, nullptr, midb, M_, 4 * C_, C_);
    k_gemm<0, 1, 0, 1><<<dim3(C_ / 128, M_ / 128), 256, 0, stream>>>(
        midb, fc2wT, fc2_b + l * C_, x, x, M_, C_, 4 * C_);
  }

  k_ln<<<M_, 256, 0, stream>>>(x, lnf_w, lnf_b, hbuf);
  k_gemm256<0, 0, 0, 0><<<dim3((V_ / 256) * (M_ / 256)), 512, 0, stream>>>(
      hbuf, headwT, nullptr, nullptr, out, M_, V_, C_);
}

// Round 5
// 2340.135 us; speedup vs baseline: 1.0184x; 1.0184x over previous
//
#include <hip/hip_runtime.h>
#include <cstdint>
#include <cstddef>

typedef __bf16 bf16_t;
typedef __bf16 bf16x8 __attribute__((ext_vector_type(8)));
typedef float f32x4 __attribute__((ext_vector_type(4)));
typedef int i32x4 __attribute__((ext_vector_type(4)));

#define B_ 4
#define T_ 1024
#define C_ 1024
#define H_ 16
#define L_ 6
#define V_ 32000
#define M_ (B_ * T_)   // 4096

// ---------------------------------------------------------------- embedding
__global__ __launch_bounds__(256) void k_embed(const int* __restrict__ idx,
                                               const float* __restrict__ tok,
                                               const float* __restrict__ pos,
                                               float* __restrict__ x) {
  int row = blockIdx.x;            // b*T + t
  int t = row & (T_ - 1);
  int id = idx[row];
  int c = threadIdx.x * 4;
  f32x4 a = *(const f32x4*)(tok + (size_t)id * C_ + c);
  f32x4 p = *(const f32x4*)(pos + (size_t)t * C_ + c);
  *(f32x4*)(x + (size_t)row * C_ + c) = a + p;
}

// ---------------------------------------------------------------- layernorm (f32 in -> bf16 out)
__global__ __launch_bounds__(256) void k_ln(const float* __restrict__ x,
                                            const float* __restrict__ w,
                                            const float* __restrict__ b,
                                            bf16_t* __restrict__ out) {
  __shared__ float red[8];
  int row = blockIdx.x;
  int tid = threadIdx.x;
  const float* xr = x + (size_t)row * C_;
  f32x4 v = *(const f32x4*)(xr + tid * 4);
  float s = v[0] + v[1] + v[2] + v[3];
  float q = v[0] * v[0] + v[1] * v[1] + v[2] * v[2] + v[3] * v[3];
#pragma unroll
  for (int off = 32; off; off >>= 1) {
    s += __shfl_xor(s, off);
    q += __shfl_xor(q, off);
  }
  int wid = tid >> 6;
  if ((tid & 63) == 0) { red[wid * 2] = s; red[wid * 2 + 1] = q; }
  __syncthreads();
  s = red[0] + red[2] + red[4] + red[6];
  q = red[1] + red[3] + red[5] + red[7];
  float mu = s * (1.f / C_);
  float var = q * (1.f / C_) - mu * mu;
  float rstd = rsqrtf(var + 1e-5f);
  f32x4 wv = *(const f32x4*)(w + tid * 4);
  f32x4 bv = *(const f32x4*)(b + tid * 4);
  bf16_t* o = out + (size_t)row * C_ + tid * 4;
#pragma unroll
  for (int j = 0; j < 4; j++) o[j] = (bf16_t)((v[j] - mu) * rstd * wv[j] + bv[j]);
}

// ------------------------------------------------- f32 [K][N] -> bf16 [N][K] transpose
__global__ __launch_bounds__(256) void k_transpose_bf16(const float* __restrict__ in,
                                                        bf16_t* __restrict__ out,
                                                        int K, int N) {
  __shared__ float tile[32][33];
  int n0 = blockIdx.x * 32, k0 = blockIdx.y * 32;
  int tid = threadIdx.x;
  int cr = tid >> 5, cc = tid & 31;
#pragma unroll
  for (int it = 0; it < 4; it++) {
    int r = it * 8 + cr;
    tile[r][cc] = in[(size_t)(k0 + r) * N + n0 + cc];
  }
  __syncthreads();
#pragma unroll
  for (int it = 0; it < 4; it++) {
    int r = it * 8 + cr;                       // local n
    out[(size_t)(n0 + r) * K + k0 + cc] = (bf16_t)tile[cc][r];
  }
}

// ------------------------------------------------- split qkv -> q (scaled), k in [B][H][T][D]
__global__ __launch_bounds__(256) void k_reshape_qk(const bf16_t* __restrict__ qkv,
                                                    bf16_t* __restrict__ qh,
                                                    bf16_t* __restrict__ kh) {
  int g = blockIdx.x * 256 + threadIdx.x;      // ((b*H+h)*T + t)*64 + d
  int d = g & 63;
  int t = (g >> 6) & (T_ - 1);
  int h = (g >> 16) & (H_ - 1);
  int b = g >> 20;
  size_t src = ((size_t)(b * T_ + t)) * (3 * C_) + h * 64 + d;
  qh[g] = (bf16_t)((float)qkv[src] * 0.125f);  // 1/sqrt(64), exact pow2
  kh[g] = qkv[src + C_];
}

// ------------------------------------------------- v -> vT [B][H][D][T]
__global__ __launch_bounds__(256) void k_vtrans(const bf16_t* __restrict__ qkv,
                                                bf16_t* __restrict__ vT) {
  __shared__ bf16_t tile[64][65];
  int bh = blockIdx.x;
  int t0 = blockIdx.y * 64;
  int tid = threadIdx.x;
  int c = tid & 63, rr = tid >> 6;
  int b = bh >> 4, h = bh & (H_ - 1);
  const bf16_t* src = qkv + ((size_t)(b * T_ + t0)) * (3 * C_) + 2 * C_ + h * 64;
#pragma unroll
  for (int it = 0; it < 16; it++) {
    int r = it * 4 + rr;
    tile[r][c] = src[(size_t)r * (3 * C_) + c];
  }
  __syncthreads();
  bf16_t* dst = vT + (size_t)bh * 64 * T_ + t0;
#pragma unroll
  for (int it = 0; it < 16; it++) {
    int dr = it * 4 + rr;                      // d
    dst[(size_t)dr * T_ + c] = tile[c][dr];
  }
}

// ---------------------------------------------------------------- flash attention
__global__ __launch_bounds__(256) void k_attn(const bf16_t* __restrict__ qh,
                                              const bf16_t* __restrict__ kh,
                                              const bf16_t* __restrict__ vT,
                                              bf16_t* __restrict__ outb) {
  __shared__ bf16_t p_lds[4][16 * 32];
  int tid = threadIdx.x, lane = tid & 63, wid = tid >> 6;
  int bh = blockIdx.x;
  int b = bh >> 4, h = bh & (H_ - 1);
  int qbase = blockIdx.y * 64 + wid * 16;
  const bf16_t* qp = qh + ((size_t)bh * T_ + qbase) * 64;
  const bf16_t* kp = kh + (size_t)bh * T_ * 64;
  const bf16_t* vp = vT + (size_t)bh * 64 * T_;
  int r = lane & 15, g = lane >> 4;

  bf16x8 qf0 = *(const bf16x8*)(qp + r * 64 + g * 8);
  bf16x8 qf1 = *(const bf16x8*)(qp + r * 64 + 32 + g * 8);

  f32x4 o[4];
  float m[4], l[4];
#pragma unroll
  for (int j = 0; j < 4; j++) { m[j] = -1e30f; l[j] = 0.f; o[j] = (f32x4){0.f, 0.f, 0.f, 0.f}; }

  int kv_end = qbase + 16;
  for (int jb = 0; jb < kv_end; jb += 32) {
    f32x4 s0 = (f32x4){0.f, 0.f, 0.f, 0.f};
    f32x4 s1 = (f32x4){0.f, 0.f, 0.f, 0.f};
    const bf16_t* kb0 = kp + (size_t)(jb + r) * 64 + g * 8;
    const bf16_t* kb1 = kb0 + 16 * 64;
    s0 = __builtin_amdgcn_mfma_f32_16x16x32_bf16(qf0, *(const bf16x8*)(kb0), s0, 0, 0, 0);
    s0 = __builtin_amdgcn_mfma_f32_16x16x32_bf16(qf1, *(const bf16x8*)(kb0 + 32), s0, 0, 0, 0);
    s1 = __builtin_amdgcn_mfma_f32_16x16x32_bf16(qf0, *(const bf16x8*)(kb1), s1, 0, 0, 0);
    s1 = __builtin_amdgcn_mfma_f32_16x16x32_bf16(qf1, *(const bf16x8*)(kb1 + 32), s1, 0, 0, 0);

    float p0[4], p1[4], fac[4];
#pragma unroll
    for (int j = 0; j < 4; j++) {
      int rowg = qbase + g * 4 + j;
      float v0 = s0[j], v1 = s1[j];
      if (jb + r > rowg) v0 = -1e30f;
      if (jb + 16 + r > rowg) v1 = -1e30f;
      float t = fmaxf(v0, v1);
      t = fmaxf(t, __shfl_xor(t, 1));
      t = fmaxf(t, __shfl_xor(t, 2));
      t = fmaxf(t, __shfl_xor(t, 4));
      t = fmaxf(t, __shfl_xor(t, 8));
      float nm = fmaxf(m[j], t);
      p0[j] = __expf(v0 - nm);
      p1[j] = __expf(v1 - nm);
      float f = __expf(m[j] - nm);
      float ts = p0[j] + p1[j];
      ts += __shfl_xor(ts, 1);
      ts += __shfl_xor(ts, 2);
      ts += __shfl_xor(ts, 4);
      ts += __shfl_xor(ts, 8);
      l[j] = l[j] * f + ts;
      m[j] = nm;
      fac[j] = f;
    }
    f32x4 fv = (f32x4){fac[0], fac[1], fac[2], fac[3]};
#pragma unroll
    for (int d = 0; d < 4; d++) o[d] *= fv;

    bf16_t* pl = p_lds[wid];
#pragma unroll
    for (int j = 0; j < 4; j++) {
      pl[(g * 4 + j) * 32 + r] = (bf16_t)p0[j];
      pl[(g * 4 + j) * 32 + 16 + r] = (bf16_t)p1[j];
    }
    bf16x8 pa = *(const bf16x8*)(pl + r * 32 + g * 8);
#pragma unroll
    for (int d = 0; d < 4; d++) {
      const bf16_t* vf = vp + (size_t)(d * 16 + r) * T_ + jb + g * 8;
      o[d] = __builtin_amdgcn_mfma_f32_16x16x32_bf16(pa, *(const bf16x8*)(vf), o[d], 0, 0, 0);
    }
  }

#pragma unroll
  for (int d = 0; d < 4; d++) {
#pragma unroll
    for (int j = 0; j < 4; j++) {
      float val = o[d][j] / l[j];
      outb[((size_t)(b * T_ + qbase + g * 4 + j)) * C_ + h * 64 + d * 16 + r] = (bf16_t)val;
    }
  }
}

// ---------------------------------------------------------------- shared helpers
__device__ __forceinline__ void gld_lds16(const bf16_t* g, bf16_t* l) {
  __builtin_amdgcn_global_load_lds((const __attribute__((address_space(1))) void*)g,
                                   (__attribute__((address_space(3))) void*)l, 16, 0, 0);
}
__device__ __forceinline__ bf16x8 lds_rd128(uint32_t addr) {
  i32x4 d;
  asm volatile("ds_read_b128 %0, %1" : "=v"(d) : "v"(addr));
  return __builtin_bit_cast(bf16x8, d);
}
#define BAR_() __builtin_amdgcn_s_barrier()
#define SCHED0_() __builtin_amdgcn_sched_barrier(0)
#define WLGN_(n)                                                           \
  do {                                                                     \
    asm volatile("s_waitcnt lgkmcnt(" #n ")" ::: "memory");                \
    SCHED0_();                                                             \
  } while (0)

// ---------------------------------------------------------------- 128x128 2-phase GEMM (small grids)
template <int OUTBF, int HASB, int HASRELU, int HASRES>
__global__ __launch_bounds__(256) void k_gemm(const bf16_t* __restrict__ A,
                                              const bf16_t* __restrict__ Bt,
                                              const float* __restrict__ bias,
                                              const float* resid,
                                              void* Cout, int M, int N, int K) {
  __shared__ bf16_t As[2][128 * 32];
  __shared__ bf16_t Bs[2][128 * 32];
  int tid = threadIdx.x;
  int lane = tid & 63, wid = tid >> 6;
  size_t rowBase = (size_t)blockIdx.y * 128;
  size_t colBase = (size_t)blockIdx.x * 128;

  const bf16_t* gA = A + (rowBase + (tid >> 2)) * (size_t)K + (tid & 3) * 8;
  const bf16_t* gB = Bt + (colBase + (tid >> 2)) * (size_t)K + (tid & 3) * 8;
  const size_t gStep64 = (size_t)64 * K;

  f32x4 acc[4][4];
#pragma unroll
  for (int i = 0; i < 4; i++)
#pragma unroll
    for (int j = 0; j < 4; j++) acc[i][j] = (f32x4){0.f, 0.f, 0.f, 0.f};

  int NK = K >> 5;
  {
    bf16_t* la = &As[0][0] + wid * 512;
    bf16_t* lb = &Bs[0][0] + wid * 512;
    gld_lds16(gA, la);            gld_lds16(gA + gStep64, la + 2048);
    gld_lds16(gB, lb);            gld_lds16(gB + gStep64, lb + 2048);
  }

  int wr = (wid >> 1) * 64, wc = (wid & 1) * 64;
  int r15 = lane & 15, g4 = lane >> 4;

  for (int kt = 0; kt < NK; kt++) {
    int buf = kt & 1;
    __syncthreads();
    if (kt + 1 < NK) {
      const bf16_t* ga = gA + (size_t)(kt + 1) * 32;
      const bf16_t* gb = gB + (size_t)(kt + 1) * 32;
      bf16_t* la = &As[buf ^ 1][0] + wid * 512;
      bf16_t* lb = &Bs[buf ^ 1][0] + wid * 512;
      gld_lds16(ga, la);          gld_lds16(ga + gStep64, la + 2048);
      gld_lds16(gb, lb);          gld_lds16(gb + gStep64, lb + 2048);
    }
    const bf16_t* as = &As[buf][0] + (wr + r15) * 32 + g4 * 8;
    const bf16_t* bs = &Bs[buf][0] + (wc + r15) * 32 + g4 * 8;
    bf16x8 af[4], bfr[4];
#pragma unroll
    for (int i = 0; i < 4; i++) af[i] = *(const bf16x8*)(as + i * 16 * 32);
#pragma unroll
    for (int i = 0; i < 4; i++) bfr[i] = *(const bf16x8*)(bs + i * 16 * 32);
#pragma unroll
    for (int i = 0; i < 4; i++)
#pragma unroll
      for (int j = 0; j < 4; j++)
        acc[i][j] = __builtin_amdgcn_mfma_f32_16x16x32_bf16(af[i], bfr[j], acc[i][j], 0, 0, 0);
  }

#pragma unroll
  for (int i = 0; i < 4; i++) {
    size_t row0 = rowBase + wr + i * 16 + g4 * 4;
#pragma unroll
    for (int j = 0; j < 4; j++) {
      size_t col = colBase + wc + j * 16 + r15;
      float bi = HASB ? bias[col] : 0.f;
#pragma unroll
      for (int q = 0; q < 4; q++) {
        size_t row = row0 + q;
        float v = acc[i][j][q] + bi;
        if (HASRELU) v = fmaxf(v, 0.f);
        if (HASRES) v += resid[row * (size_t)N + col];
        if (OUTBF)
          ((bf16_t*)Cout)[row * (size_t)N + col] = (bf16_t)v;
        else
          ((float*)Cout)[row * (size_t)N + col] = v;
      }
    }
  }
}

// ---------------------------------------------------------------- 256x256 pipelined GEMM
// BM=BN=256, BK=64, 8 waves (2Mx4N), per-wave 128x64 out.
// T2 swizzle (3-bit): physical_byte = row*128 + (intra ^ ((row&7)<<4)).
// In-wave fragment double-buffering: two register sets (half-K-tile each);
// ds_read of set S^1 issues before MFMA on set S -> reads hide under MFMA.
// 2 barriers / K-tile. lgkmcnt(12) = wait older set only (in-order DS).
#define STAGE_(q, tk, bufv)                                                           \
  do {                                                                                \
    const bf16_t* _ga = A + (size_t)(rowBase + (q)*64 + srow) * (size_t)K +           \
                        (size_t)(tk)*64 + scol;                                       \
    const bf16_t* _gb = Bt + (size_t)(colBase + (q)*64 + srow) * (size_t)K +          \
                        (size_t)(tk)*64 + scol;                                       \
    gld_lds16(_ga, AsF + (bufv)*16384 + (q)*4096 + w * 512);                          \
    gld_lds16(_gb, BsF + (bufv)*16384 + (q)*4096 + w * 512);                          \
  } while (0)

// read one half-K (kk in {0,1}) of A (8 frags) and B (4 frags) from buffer bufv
#define RDS_(aset, bset, kk, bufv)                                                    \
  do {                                                                                \
    uint32_t _off = (kk) ? offK1 : offK0;                                             \
    uint32_t _ab = aRd + (uint32_t)(bufv)*32768u + _off;                              \
    uint32_t _bb = bRd + (uint32_t)(bufv)*32768u + _off;                              \
    _Pragma("unroll") for (int _m = 0; _m < 8; _m++)                                  \
        aset[_m] = lds_rd128(_ab + _m * 2048);                                        \
    _Pragma("unroll") for (int _n = 0; _n < 4; _n++)                                  \
        bset[_n] = lds_rd128(_bb + _n * 2048);                                        \
  } while (0)

#define MFH_(aset, bset)                                                              \
  do {                                                                                \
    __builtin_amdgcn_s_setprio(1);                                                    \
    _Pragma("unroll") for (int _m = 0; _m < 8; _m++)                                  \
        _Pragma("unroll") for (int _n = 0; _n < 4; _n++)                              \
            acc[_m][_n] = __builtin_amdgcn_mfma_f32_16x16x32_bf16(                    \
                aset[_m], bset[_n], acc[_m][_n], 0, 0, 0);                            \
    __builtin_amdgcn_s_setprio(0);                                                    \
  } while (0)

template <int OUTBF, int HASB, int HASRELU, int HASRES>
__global__ __launch_bounds__(512, 2) void k_gemm256(const bf16_t* __restrict__ A,
                                                    const bf16_t* __restrict__ Bt,
                                                    const float* __restrict__ bias,
                                                    const float* resid,
                                                    void* Cout, int M, int N, int K) {
  __shared__ bf16_t As[2][256][64];
  __shared__ bf16_t Bs[2][256][64];
  bf16_t* AsF = &As[0][0][0];
  bf16_t* BsF = &Bs[0][0][0];
  const uint32_t asb = (uint32_t)(uintptr_t)AsF;
  const uint32_t bsb = (uint32_t)(uintptr_t)BsF;

  int tid = threadIdx.x, lane = tid & 63, w = tid >> 6;
  int wr = w >> 2, wc = w & 3;
  int r15 = lane & 15, g4 = lane >> 4;

  // XCD-bijective swizzle, column-major decomposition (consecutive -> same B panel)
  int nwg = (int)gridDim.x;
  int bid = (int)blockIdx.x;
  int xcd = bid & 7, loc = bid >> 3;
  int q8 = nwg >> 3, r8 = nwg & 7;
  int swz = (xcd < r8) ? xcd * (q8 + 1) + loc : r8 * (q8 + 1) + (xcd - r8) * q8 + loc;
  int nY = M >> 8;
  int by = swz % nY, bx = swz / nY;
  int rowBase = by * 256, colBase = bx * 256;

  // stage source: linear LDS dest; global col pre-applies inverse 3-bit XOR
  int srow = w * 8 + (lane >> 3);
  int scol = ((lane & 7) ^ (lane >> 3)) * 8;

  // read-side: row-base (no XOR) + intra-row offset XOR'd with (row&7)<<4
  uint32_t xm = (uint32_t)((r15 & 7) << 4);
  uint32_t offK0 = ((uint32_t)(g4 * 16)) ^ xm;
  uint32_t offK1 = ((uint32_t)(g4 * 16 + 64)) ^ xm;
  uint32_t aRd = asb + (uint32_t)((wr * 128 + r15) * 128);
  uint32_t bRd = bsb + (uint32_t)((wc * 64 + r15) * 128);

  f32x4 acc[8][4];
#pragma unroll
  for (int i = 0; i < 8; i++)
#pragma unroll
    for (int j = 0; j < 4; j++) acc[i][j] = (f32x4){0.f, 0.f, 0.f, 0.f};

  bf16x8 a0[8], a1[8], b0[4], b1[4];

  // prologue: stage tile 0, read set0 <- (tile0, half0)
#pragma unroll
  for (int q = 0; q < 4; q++) STAGE_(q, 0, 0);
  asm volatile("s_waitcnt vmcnt(0)" ::: "memory");
  BAR_();
  RDS_(a0, b0, 0, 0);

  int NT = K >> 6;
  for (int kt = 0; kt < NT; ++kt) {
    int buf = kt & 1;
    bool pf = (kt + 1 < NT);
    // stage next tile into buf^1 (safe: end-of-prev-iter barrier drained buf^1 reads)
    if (pf) {
#pragma unroll
      for (int q = 0; q < 4; q++) STAGE_(q, kt + 1, buf ^ 1);
    }
    // prefetch set1 <- (kt, half1); compute half0 while it lands
    RDS_(a1, b1, 1, buf);
    WLGN_(12);                 // set0 ready (oldest 12 DS ops drained)
    MFH_(a0, b0);
    if (pf) {
      asm volatile("s_waitcnt vmcnt(0)" ::: "memory");  // stage(kt+1) landed
      BAR_();                                           // visible to all waves
      RDS_(a0, b0, 0, buf ^ 1);                         // prefetch next tile half0
      WLGN_(12);               // set1 ready
    } else {
      WLGN_(0);
    }
    MFH_(a1, b1);
    BAR_();                    // protect buf from next iter's stage overwrite
  }

#pragma unroll
  for (int m = 0; m < 8; m++) {
    size_t row0 = (size_t)rowBase + wr * 128 + m * 16 + g4 * 4;
#pragma unroll
    for (int n = 0; n < 4; n++) {
      size_t col = (size_t)colBase + wc * 64 + n * 16 + r15;
      float bi = HASB ? bias[col] : 0.f;
#pragma unroll
      for (int qq = 0; qq < 4; qq++) {
        size_t row = row0 + qq;
        float v = acc[m][n][qq] + bi;
        if (HASRELU) v = fmaxf(v, 0.f);
        if (HASRES) v += resid[row * (size_t)N + col];
        if (OUTBF)
          ((bf16_t*)Cout)[row * (size_t)N + col] = (bf16_t)v;
        else
          ((float*)Cout)[row * (size_t)N + col] = v;
      }
    }
  }
}

// ---------------------------------------------------------------- launch
extern "C" void kernel_launch(void* const* d_in, const int* in_sizes, int n_in,
                              void* d_out, int out_size, void* d_ws, size_t ws_size,
                              hipStream_t stream) {
  (void)in_sizes; (void)n_in; (void)out_size; (void)ws_size;
  const int* idx = (const int*)d_in[0];
  const float* tok_emb = (const float*)d_in[1];
  const float* pos_emb = (const float*)d_in[2];
  const float* qkv_w = (const float*)d_in[3];
  const float* attn_out_w = (const float*)d_in[4];
  const float* attn_out_b = (const float*)d_in[5];
  const float* fc1_w = (const float*)d_in[6];
  const float* fc1_b = (const float*)d_in[7];
  const float* fc2_w = (const float*)d_in[8];
  const float* fc2_b = (const float*)d_in[9];
  const float* ln1_w = (const float*)d_in[10];
  const float* ln1_b = (const float*)d_in[11];
  const float* ln2_w = (const float*)d_in[12];
  const float* ln2_b = (const float*)d_in[13];
  const float* lnf_w = (const float*)d_in[14];
  const float* lnf_b = (const float*)d_in[15];
  const float* head_w = (const float*)d_in[16];
  float* out = (float*)d_out;

  char* wsp = (char*)d_ws;
  auto alloc = [&](size_t bytes) {
    char* p = wsp;
    wsp += (bytes + 255) & ~(size_t)255;
    return p;
  };
  float* x      = (float*)alloc((size_t)M_ * C_ * 4);
  bf16_t* hbuf  = (bf16_t*)alloc((size_t)M_ * C_ * 2);
  bf16_t* qkvb  = (bf16_t*)alloc((size_t)M_ * 3 * C_ * 2);
  bf16_t* qhb   = (bf16_t*)alloc((size_t)M_ * C_ * 2);
  bf16_t* khb   = (bf16_t*)alloc((size_t)M_ * C_ * 2);
  bf16_t* vTb   = (bf16_t*)alloc((size_t)M_ * C_ * 2);
  bf16_t* attnb = (bf16_t*)alloc((size_t)M_ * C_ * 2);
  bf16_t* midb  = (bf16_t*)alloc((size_t)M_ * 4 * C_ * 2);
  bf16_t* qkvwT = (bf16_t*)alloc((size_t)3 * C_ * C_ * 2);
  bf16_t* owT   = (bf16_t*)alloc((size_t)C_ * C_ * 2);
  bf16_t* fc1wT = (bf16_t*)alloc((size_t)4 * C_ * C_ * 2);
  bf16_t* fc2wT = (bf16_t*)alloc((size_t)4 * C_ * C_ * 2);
  bf16_t* headwT= (bf16_t*)alloc((size_t)C_ * V_ * 2);

  k_embed<<<M_, 256, 0, stream>>>(idx, tok_emb, pos_emb, x);
  k_transpose_bf16<<<dim3(V_ / 32, C_ / 32), 256, 0, stream>>>(head_w, headwT, C_, V_);

  for (int l = 0; l < L_; l++) {
    k_transpose_bf16<<<dim3(3 * C_ / 32, C_ / 32), 256, 0, stream>>>(
        qkv_w + (size_t)l * C_ * 3 * C_, qkvwT, C_, 3 * C_);
    k_transpose_bf16<<<dim3(C_ / 32, C_ / 32), 256, 0, stream>>>(
        attn_out_w + (size_t)l * C_ * C_, owT, C_, C_);
    k_transpose_bf16<<<dim3(4 * C_ / 32, C_ / 32), 256, 0, stream>>>(
        fc1_w + (size_t)l * C_ * 4 * C_, fc1wT, C_, 4 * C_);
    k_transpose_bf16<<<dim3(C_ / 32, 4 * C_ / 32), 256, 0, stream>>>(
        fc2_w + (size_t)l * 4 * C_ * C_, fc2wT, 4 * C_, C_);

    k_ln<<<M_, 256, 0, stream>>>(x, ln1_w + l * C_, ln1_b + l * C_, hbuf);
    k_gemm256<1, 0, 0, 0><<<dim3((3 * C_ / 256) * (M_ / 256)), 512, 0, stream>>>(
        hbuf, qkvwT, nullptr, nullptr, qkvb, M_, 3 * C_, C_);
    k_reshape_qk<<<(M_ * C_) / 256, 256, 0, stream>>>(qkvb, qhb, khb);
    k_vtrans<<<dim3(B_ * H_, T_ / 64), 256, 0, stream>>>(qkvb, vTb);
    k_attn<<<dim3(B_ * H_, T_ / 64), 256, 0, stream>>>(qhb, khb, vTb, attnb);
    k_gemm<0, 1, 0, 1><<<dim3(C_ / 128, M_ / 128), 256, 0, stream>>>(
        attnb, owT, attn_out_b + l * C_, x, x, M_, C_, C_);

    k_ln<<<M_, 256, 0, stream>>>(x, ln2_w + l * C_, ln2_b + l * C_, hbuf);
    k_gemm256<1, 1, 1, 0><<<dim3((4 * C_ / 256) * (M_ / 256)), 512, 0, stream>>>(
        hbuf, fc1wT, fc1_b + (size_t)l * 4 * C_, nullptr, midb, M_, 4 * C_, C_);
    k_gemm<0, 1, 0, 1><<<dim3(C_ / 128, M_ / 128), 256, 0, stream>>>(
        midb, fc2wT, fc2_b + l * C_, x, x, M_, C_, 4 * C_);
  }

  k_ln<<<M_, 256, 0, stream>>>(x, lnf_w, lnf_b, hbuf);
  k_gemm256<0, 0, 0, 0><<<dim3((V_ / 256) * (M_ / 256)), 512, 0, stream>>>(
      hbuf, headwT, nullptr, nullptr, out, M_, V_, C_);
}

// Round 6
// 2248.493 us; speedup vs baseline: 1.0599x; 1.0408x over previous
//
#include <hip/hip_runtime.h>
#include <cstdint>
#include <cstddef>

typedef __bf16 bf16_t;
typedef __bf16 bf16x8 __attribute__((ext_vector_type(8)));
typedef float f32x4 __attribute__((ext_vector_type(4)));
typedef int i32x4 __attribute__((ext_vector_type(4)));

#define B_ 4
#define T_ 1024
#define C_ 1024
#define H_ 16
#define L_ 6
#define V_ 32000
#define M_ (B_ * T_)   // 4096

// ---------------------------------------------------------------- embedding
__global__ __launch_bounds__(256) void k_embed(const int* __restrict__ idx,
                                               const float* __restrict__ tok,
                                               const float* __restrict__ pos,
                                               float* __restrict__ x) {
  int row = blockIdx.x;            // b*T + t
  int t = row & (T_ - 1);
  int id = idx[row];
  int c = threadIdx.x * 4;
  f32x4 a = *(const f32x4*)(tok + (size_t)id * C_ + c);
  f32x4 p = *(const f32x4*)(pos + (size_t)t * C_ + c);
  *(f32x4*)(x + (size_t)row * C_ + c) = a + p;
}

// ---------------------------------------------------------------- layernorm (f32 in -> bf16 out)
__global__ __launch_bounds__(256) void k_ln(const float* __restrict__ x,
                                            const float* __restrict__ w,
                                            const float* __restrict__ b,
                                            bf16_t* __restrict__ out) {
  __shared__ float red[8];
  int row = blockIdx.x;
  int tid = threadIdx.x;
  const float* xr = x + (size_t)row * C_;
  f32x4 v = *(const f32x4*)(xr + tid * 4);
  float s = v[0] + v[1] + v[2] + v[3];
  float q = v[0] * v[0] + v[1] * v[1] + v[2] * v[2] + v[3] * v[3];
#pragma unroll
  for (int off = 32; off; off >>= 1) {
    s += __shfl_xor(s, off);
    q += __shfl_xor(q, off);
  }
  int wid = tid >> 6;
  if ((tid & 63) == 0) { red[wid * 2] = s; red[wid * 2 + 1] = q; }
  __syncthreads();
  s = red[0] + red[2] + red[4] + red[6];
  q = red[1] + red[3] + red[5] + red[7];
  float mu = s * (1.f / C_);
  float var = q * (1.f / C_) - mu * mu;
  float rstd = rsqrtf(var + 1e-5f);
  f32x4 wv = *(const f32x4*)(w + tid * 4);
  f32x4 bv = *(const f32x4*)(b + tid * 4);
  bf16_t* o = out + (size_t)row * C_ + tid * 4;
#pragma unroll
  for (int j = 0; j < 4; j++) o[j] = (bf16_t)((v[j] - mu) * rstd * wv[j] + bv[j]);
}

// ------------------------------------------------- f32 [K][N] -> bf16 [N][K] transpose
__global__ __launch_bounds__(256) void k_transpose_bf16(const float* __restrict__ in,
                                                        bf16_t* __restrict__ out,
                                                        int K, int N) {
  __shared__ float tile[32][33];
  int n0 = blockIdx.x * 32, k0 = blockIdx.y * 32;
  int tid = threadIdx.x;
  int cr = tid >> 5, cc = tid & 31;
#pragma unroll
  for (int it = 0; it < 4; it++) {
    int r = it * 8 + cr;
    tile[r][cc] = in[(size_t)(k0 + r) * N + n0 + cc];
  }
  __syncthreads();
#pragma unroll
  for (int it = 0; it < 4; it++) {
    int r = it * 8 + cr;                       // local n
    out[(size_t)(n0 + r) * K + k0 + cc] = (bf16_t)tile[cc][r];
  }
}

// ------------------------------------------------- split qkv -> q (scaled), k in [B][H][T][D]
__global__ __launch_bounds__(256) void k_reshape_qk(const bf16_t* __restrict__ qkv,
                                                    bf16_t* __restrict__ qh,
                                                    bf16_t* __restrict__ kh) {
  int g = blockIdx.x * 256 + threadIdx.x;      // ((b*H+h)*T + t)*64 + d
  int d = g & 63;
  int t = (g >> 6) & (T_ - 1);
  int h = (g >> 16) & (H_ - 1);
  int b = g >> 20;
  size_t src = ((size_t)(b * T_ + t)) * (3 * C_) + h * 64 + d;
  qh[g] = (bf16_t)((float)qkv[src] * 0.125f);  // 1/sqrt(64), exact pow2
  kh[g] = qkv[src + C_];
}

// ------------------------------------------------- v -> vT [B][H][D][T]
__global__ __launch_bounds__(256) void k_vtrans(const bf16_t* __restrict__ qkv,
                                                bf16_t* __restrict__ vT) {
  __shared__ bf16_t tile[64][65];
  int bh = blockIdx.x;
  int t0 = blockIdx.y * 64;
  int tid = threadIdx.x;
  int c = tid & 63, rr = tid >> 6;
  int b = bh >> 4, h = bh & (H_ - 1);
  const bf16_t* src = qkv + ((size_t)(b * T_ + t0)) * (3 * C_) + 2 * C_ + h * 64;
#pragma unroll
  for (int it = 0; it < 16; it++) {
    int r = it * 4 + rr;
    tile[r][c] = src[(size_t)r * (3 * C_) + c];
  }
  __syncthreads();
  bf16_t* dst = vT + (size_t)bh * 64 * T_ + t0;
#pragma unroll
  for (int it = 0; it < 16; it++) {
    int dr = it * 4 + rr;                      // d
    dst[(size_t)dr * T_ + c] = tile[c][dr];
  }
}

// ---------------------------------------------------------------- flash attention
__global__ __launch_bounds__(256) void k_attn(const bf16_t* __restrict__ qh,
                                              const bf16_t* __restrict__ kh,
                                              const bf16_t* __restrict__ vT,
                                              bf16_t* __restrict__ outb) {
  __shared__ bf16_t p_lds[4][16 * 32];
  int tid = threadIdx.x, lane = tid & 63, wid = tid >> 6;
  int bh = blockIdx.x;
  int b = bh >> 4, h = bh & (H_ - 1);
  int qbase = blockIdx.y * 64 + wid * 16;
  const bf16_t* qp = qh + ((size_t)bh * T_ + qbase) * 64;
  const bf16_t* kp = kh + (size_t)bh * T_ * 64;
  const bf16_t* vp = vT + (size_t)bh * 64 * T_;
  int r = lane & 15, g = lane >> 4;

  bf16x8 qf0 = *(const bf16x8*)(qp + r * 64 + g * 8);
  bf16x8 qf1 = *(const bf16x8*)(qp + r * 64 + 32 + g * 8);

  f32x4 o[4];
  float m[4], l[4];
#pragma unroll
  for (int j = 0; j < 4; j++) { m[j] = -1e30f; l[j] = 0.f; o[j] = (f32x4){0.f, 0.f, 0.f, 0.f}; }

  int kv_end = qbase + 16;
  for (int jb = 0; jb < kv_end; jb += 32) {
    f32x4 s0 = (f32x4){0.f, 0.f, 0.f, 0.f};
    f32x4 s1 = (f32x4){0.f, 0.f, 0.f, 0.f};
    const bf16_t* kb0 = kp + (size_t)(jb + r) * 64 + g * 8;
    const bf16_t* kb1 = kb0 + 16 * 64;
    s0 = __builtin_amdgcn_mfma_f32_16x16x32_bf16(qf0, *(const bf16x8*)(kb0), s0, 0, 0, 0);
    s0 = __builtin_amdgcn_mfma_f32_16x16x32_bf16(qf1, *(const bf16x8*)(kb0 + 32), s0, 0, 0, 0);
    s1 = __builtin_amdgcn_mfma_f32_16x16x32_bf16(qf0, *(const bf16x8*)(kb1), s1, 0, 0, 0);
    s1 = __builtin_amdgcn_mfma_f32_16x16x32_bf16(qf1, *(const bf16x8*)(kb1 + 32), s1, 0, 0, 0);

    float p0[4], p1[4], fac[4];
#pragma unroll
    for (int j = 0; j < 4; j++) {
      int rowg = qbase + g * 4 + j;
      float v0 = s0[j], v1 = s1[j];
      if (jb + r > rowg) v0 = -1e30f;
      if (jb + 16 + r > rowg) v1 = -1e30f;
      float t = fmaxf(v0, v1);
      t = fmaxf(t, __shfl_xor(t, 1));
      t = fmaxf(t, __shfl_xor(t, 2));
      t = fmaxf(t, __shfl_xor(t, 4));
      t = fmaxf(t, __shfl_xor(t, 8));
      float nm = fmaxf(m[j], t);
      p0[j] = __expf(v0 - nm);
      p1[j] = __expf(v1 - nm);
      float f = __expf(m[j] - nm);
      float ts = p0[j] + p1[j];
      ts += __shfl_xor(ts, 1);
      ts += __shfl_xor(ts, 2);
      ts += __shfl_xor(ts, 4);
      ts += __shfl_xor(ts, 8);
      l[j] = l[j] * f + ts;
      m[j] = nm;
      fac[j] = f;
    }
    f32x4 fv = (f32x4){fac[0], fac[1], fac[2], fac[3]};
#pragma unroll
    for (int d = 0; d < 4; d++) o[d] *= fv;

    bf16_t* pl = p_lds[wid];
#pragma unroll
    for (int j = 0; j < 4; j++) {
      pl[(g * 4 + j) * 32 + r] = (bf16_t)p0[j];
      pl[(g * 4 + j) * 32 + 16 + r] = (bf16_t)p1[j];
    }
    bf16x8 pa = *(const bf16x8*)(pl + r * 32 + g * 8);
#pragma unroll
    for (int d = 0; d < 4; d++) {
      const bf16_t* vf = vp + (size_t)(d * 16 + r) * T_ + jb + g * 8;
      o[d] = __builtin_amdgcn_mfma_f32_16x16x32_bf16(pa, *(const bf16x8*)(vf), o[d], 0, 0, 0);
    }
  }

#pragma unroll
  for (int d = 0; d < 4; d++) {
#pragma unroll
    for (int j = 0; j < 4; j++) {
      float val = o[d][j] / l[j];
      outb[((size_t)(b * T_ + qbase + g * 4 + j)) * C_ + h * 64 + d * 16 + r] = (bf16_t)val;
    }
  }
}

// ---------------------------------------------------------------- shared helpers
__device__ __forceinline__ void gld_lds16(const bf16_t* g, bf16_t* l) {
  __builtin_amdgcn_global_load_lds((const __attribute__((address_space(1))) void*)g,
                                   (__attribute__((address_space(3))) void*)l, 16, 0, 0);
}
__device__ __forceinline__ bf16x8 lds_rd128(uint32_t addr) {
  i32x4 d;
  asm volatile("ds_read_b128 %0, %1" : "=v"(d) : "v"(addr));
  return __builtin_bit_cast(bf16x8, d);
}
#define BAR_() __builtin_amdgcn_s_barrier()
#define SCHED0_() __builtin_amdgcn_sched_barrier(0)
#define WLGN_(n)                                                           \
  do {                                                                     \
    asm volatile("s_waitcnt lgkmcnt(" #n ")" ::: "memory");                \
    SCHED0_();                                                             \
  } while (0)

// ---------------------------------------------------------------- 128x128 2-phase GEMM
// [128][32] tile; 2-bit double-XOR swizzle: phys_slot = log_slot ^ (row&3) ^ ((row>>2)&3)
// (max 2-way residual = free). Both-sides: linear gld_lds dest + inverse-swizzled
// global source; XOR'd LDS read offset. XCD-bijective col-major block swizzle.
template <int OUTBF, int HASB, int HASRELU, int HASRES>
__global__ __launch_bounds__(256) void k_gemm(const bf16_t* __restrict__ A,
                                              const bf16_t* __restrict__ Bt,
                                              const float* __restrict__ bias,
                                              const float* resid,
                                              void* Cout, int M, int N, int K) {
  __shared__ bf16_t As[2][128 * 32];
  __shared__ bf16_t Bs[2][128 * 32];
  int tid = threadIdx.x;
  int lane = tid & 63, wid = tid >> 6;

  // XCD-bijective swizzle, col-major (consecutive blocks on an XCD share B panel)
  int nwg = (int)(gridDim.x * gridDim.y);
  int bid = (int)(blockIdx.y * gridDim.x + blockIdx.x);
  int xcd = bid & 7, loc = bid >> 3;
  int q8 = nwg >> 3, r8 = nwg & 7;
  int swz = (xcd < r8) ? xcd * (q8 + 1) + loc : r8 * (q8 + 1) + (xcd - r8) * q8 + loc;
  int nY = M >> 7;
  size_t rowBase = (size_t)(swz % nY) * 128;
  size_t colBase = (size_t)(swz / nY) * 128;

  // stage: linear dest; source col pre-applies inverse 2-bit double-XOR
  int scolE = (((tid & 3) ^ ((tid >> 2) & 3) ^ ((tid >> 4) & 3)) * 8);
  const bf16_t* gA = A + (rowBase + (tid >> 2)) * (size_t)K + scolE;
  const bf16_t* gB = Bt + (colBase + (tid >> 2)) * (size_t)K + scolE;
  const size_t gStep64 = (size_t)64 * K;

  f32x4 acc[4][4];
#pragma unroll
  for (int i = 0; i < 4; i++)
#pragma unroll
    for (int j = 0; j < 4; j++) acc[i][j] = (f32x4){0.f, 0.f, 0.f, 0.f};

  int NK = K >> 5;
  {
    bf16_t* la = &As[0][0] + wid * 512;
    bf16_t* lb = &Bs[0][0] + wid * 512;
    gld_lds16(gA, la);            gld_lds16(gA + gStep64, la + 2048);
    gld_lds16(gB, lb);            gld_lds16(gB + gStep64, lb + 2048);
  }

  int wr = (wid >> 1) * 64, wc = (wid & 1) * 64;
  int r15 = lane & 15, g4 = lane >> 4;
  // read-side swizzled intra-row element offset
  uint32_t roff = (uint32_t)((g4 * 8) ^ (((r15 & 3) ^ ((r15 >> 2) & 3)) << 3));

  for (int kt = 0; kt < NK; kt++) {
    int buf = kt & 1;
    __syncthreads();
    if (kt + 1 < NK) {
      const bf16_t* ga = gA + (size_t)(kt + 1) * 32;
      const bf16_t* gb = gB + (size_t)(kt + 1) * 32;
      bf16_t* la = &As[buf ^ 1][0] + wid * 512;
      bf16_t* lb = &Bs[buf ^ 1][0] + wid * 512;
      gld_lds16(ga, la);          gld_lds16(ga + gStep64, la + 2048);
      gld_lds16(gb, lb);          gld_lds16(gb + gStep64, lb + 2048);
    }
    const bf16_t* asb = &As[buf][0];
    const bf16_t* bsb = &Bs[buf][0];
    bf16x8 af[4], bfr[4];
#pragma unroll
    for (int i = 0; i < 4; i++)
      af[i] = *(const bf16x8*)(asb + (wr + r15 + i * 16) * 32 + roff);
#pragma unroll
    for (int i = 0; i < 4; i++)
      bfr[i] = *(const bf16x8*)(bsb + (wc + r15 + i * 16) * 32 + roff);
#pragma unroll
    for (int i = 0; i < 4; i++)
#pragma unroll
      for (int j = 0; j < 4; j++)
        acc[i][j] = __builtin_amdgcn_mfma_f32_16x16x32_bf16(af[i], bfr[j], acc[i][j], 0, 0, 0);
  }

#pragma unroll
  for (int i = 0; i < 4; i++) {
    size_t row0 = rowBase + wr + i * 16 + g4 * 4;
#pragma unroll
    for (int j = 0; j < 4; j++) {
      size_t col = colBase + wc + j * 16 + r15;
      float bi = HASB ? bias[col] : 0.f;
#pragma unroll
      for (int q = 0; q < 4; q++) {
        size_t row = row0 + q;
        float v = acc[i][j][q] + bi;
        if (HASRELU) v = fmaxf(v, 0.f);
        if (HASRES) v += resid[row * (size_t)N + col];
        if (OUTBF)
          ((bf16_t*)Cout)[row * (size_t)N + col] = (bf16_t)v;
        else
          ((float*)Cout)[row * (size_t)N + col] = v;
      }
    }
  }
}

// ---------------------------------------------------------------- 256x256 pipelined GEMM
// BM=BN=256, BK=64, 8 waves (2Mx4N). One barrier / one counted-lgkm / one late
// vmcnt per K-tile; all 24 ds_reads issued up front; MFMA half0 overlaps the
// second 12 reads. Stage(kt+1) at tile top -> vmcnt(0) at tile end is free.
#define STAGE_(q, tk, bufv)                                                           \
  do {                                                                                \
    const bf16_t* _ga = A + (size_t)(rowBase + (q)*64 + srow) * (size_t)K +           \
                        (size_t)(tk)*64 + scol;                                       \
    const bf16_t* _gb = Bt + (size_t)(colBase + (q)*64 + srow) * (size_t)K +          \
                        (size_t)(tk)*64 + scol;                                       \
    gld_lds16(_ga, AsF + (bufv)*16384 + (q)*4096 + w * 512);                          \
    gld_lds16(_gb, BsF + (bufv)*16384 + (q)*4096 + w * 512);                          \
  } while (0)

// read one half-K (kk in {0,1}) of A (8 frags) and B (4 frags) from buffer bufv
#define RDS_(aset, bset, kk, bufv)                                                    \
  do {                                                                                \
    uint32_t _off = (kk) ? offK1 : offK0;                                             \
    uint32_t _ab = aRd + (uint32_t)(bufv)*32768u + _off;                              \
    uint32_t _bb = bRd + (uint32_t)(bufv)*32768u + _off;                              \
    _Pragma("unroll") for (int _m = 0; _m < 8; _m++)                                  \
        aset[_m] = lds_rd128(_ab + _m * 2048);                                        \
    _Pragma("unroll") for (int _n = 0; _n < 4; _n++)                                  \
        bset[_n] = lds_rd128(_bb + _n * 2048);                                        \
  } while (0)

#define MFH_(aset, bset)                                                              \
  do {                                                                                \
    __builtin_amdgcn_s_setprio(1);                                                    \
    _Pragma("unroll") for (int _m = 0; _m < 8; _m++)                                  \
        _Pragma("unroll") for (int _n = 0; _n < 4; _n++)                              \
            acc[_m][_n] = __builtin_amdgcn_mfma_f32_16x16x32_bf16(                    \
                aset[_m], bset[_n], acc[_m][_n], 0, 0, 0);                            \
    __builtin_amdgcn_s_setprio(0);                                                    \
  } while (0)

template <int OUTBF, int HASB, int HASRELU, int HASRES>
__global__ __launch_bounds__(512, 2) void k_gemm256(const bf16_t* __restrict__ A,
                                                    const bf16_t* __restrict__ Bt,
                                                    const float* __restrict__ bias,
                                                    const float* resid,
                                                    void* Cout, int M, int N, int K) {
  __shared__ bf16_t As[2][256][64];
  __shared__ bf16_t Bs[2][256][64];
  bf16_t* AsF = &As[0][0][0];
  bf16_t* BsF = &Bs[0][0][0];
  const uint32_t asb = (uint32_t)(uintptr_t)AsF;
  const uint32_t bsb = (uint32_t)(uintptr_t)BsF;

  int tid = threadIdx.x, lane = tid & 63, w = tid >> 6;
  int wr = w >> 2, wc = w & 3;
  int r15 = lane & 15, g4 = lane >> 4;

  // XCD-bijective swizzle, column-major decomposition (consecutive -> same B panel)
  int nwg = (int)gridDim.x;
  int bid = (int)blockIdx.x;
  int xcd = bid & 7, loc = bid >> 3;
  int q8 = nwg >> 3, r8 = nwg & 7;
  int swz = (xcd < r8) ? xcd * (q8 + 1) + loc : r8 * (q8 + 1) + (xcd - r8) * q8 + loc;
  int nY = M >> 8;
  int by = swz % nY, bx = swz / nY;
  int rowBase = by * 256, colBase = bx * 256;

  // stage source: linear LDS dest; global col pre-applies inverse 3-bit XOR
  int srow = w * 8 + (lane >> 3);
  int scol = ((lane & 7) ^ (lane >> 3)) * 8;

  // read-side: row-base (no XOR) + intra-row offset XOR'd with (row&7)<<4
  uint32_t xm = (uint32_t)((r15 & 7) << 4);
  uint32_t offK0 = ((uint32_t)(g4 * 16)) ^ xm;
  uint32_t offK1 = ((uint32_t)(g4 * 16 + 64)) ^ xm;
  uint32_t aRd = asb + (uint32_t)((wr * 128 + r15) * 128);
  uint32_t bRd = bsb + (uint32_t)((wc * 64 + r15) * 128);

  f32x4 acc[8][4];
#pragma unroll
  for (int i = 0; i < 8; i++)
#pragma unroll
    for (int j = 0; j < 4; j++) acc[i][j] = (f32x4){0.f, 0.f, 0.f, 0.f};

  bf16x8 a0[8], a1[8], b0[4], b1[4];

  // prologue: stage tile 0
#pragma unroll
  for (int q = 0; q < 4; q++) STAGE_(q, 0, 0);
  asm volatile("s_waitcnt vmcnt(0)" ::: "memory");
  BAR_();

  int NT = K >> 6;
  for (int kt = 0; kt < NT; ++kt) {
    int buf = kt & 1;
    bool pf = (kt + 1 < NT);
    // stage next tile into buf^1 (buf^1's reads finished before prev barrier)
    if (pf) {
#pragma unroll
      for (int q = 0; q < 4; q++) STAGE_(q, kt + 1, buf ^ 1);
    }
    // all 24 reads up front; half1's 12 overlap MFMA on half0
    RDS_(a0, b0, 0, buf);
    RDS_(a1, b1, 1, buf);
    WLGN_(12);                 // half0 frags ready (DS in-order per wave)
    MFH_(a0, b0);
    WLGN_(0);                  // half1 frags ready (likely already landed)
    MFH_(a1, b1);
    asm volatile("s_waitcnt vmcnt(0)" ::: "memory");  // stage(kt+1) landed (cheap)
    BAR_();                    // tile kt+1 visible; buf free for overwrite
  }

#pragma unroll
  for (int m = 0; m < 8; m++) {
    size_t row0 = (size_t)rowBase + wr * 128 + m * 16 + g4 * 4;
#pragma unroll
    for (int n = 0; n < 4; n++) {
      size_t col = (size_t)colBase + wc * 64 + n * 16 + r15;
      float bi = HASB ? bias[col] : 0.f;
#pragma unroll
      for (int qq = 0; qq < 4; qq++) {
        size_t row = row0 + qq;
        float v = acc[m][n][qq] + bi;
        if (HASRELU) v = fmaxf(v, 0.f);
        if (HASRES) v += resid[row * (size_t)N + col];
        if (OUTBF)
          ((bf16_t*)Cout)[row * (size_t)N + col] = (bf16_t)v;
        else
          ((float*)Cout)[row * (size_t)N + col] = v;
      }
    }
  }
}

// ---------------------------------------------------------------- launch
extern "C" void kernel_launch(void* const* d_in, const int* in_sizes, int n_in,
                              void* d_out, int out_size, void* d_ws, size_t ws_size,
                              hipStream_t stream) {
  (void)in_sizes; (void)n_in; (void)out_size; (void)ws_size;
  const int* idx = (const int*)d_in[0];
  const float* tok_emb = (const float*)d_in[1];
  const float* pos_emb = (const float*)d_in[2];
  const float* qkv_w = (const float*)d_in[3];
  const float* attn_out_w = (const float*)d_in[4];
  const float* attn_out_b = (const float*)d_in[5];
  const float* fc1_w = (const float*)d_in[6];
  const float* fc1_b = (const float*)d_in[7];
  const float* fc2_w = (const float*)d_in[8];
  const float* fc2_b = (const float*)d_in[9];
  const float* ln1_w = (const float*)d_in[10];
  const float* ln1_b = (const float*)d_in[11];
  const float* ln2_w = (const float*)d_in[12];
  const float* ln2_b = (const float*)d_in[13];
  const float* lnf_w = (const float*)d_in[14];
  const float* lnf_b = (const float*)d_in[15];
  const float* head_w = (const float*)d_in[16];
  float* out = (float*)d_out;

  char* wsp = (char*)d_ws;
  auto alloc = [&](size_t bytes) {
    char* p = wsp;
    wsp += (bytes + 255) & ~(size_t)255;
    return p;
  };
  float* x      = (float*)alloc((size_t)M_ * C_ * 4);
  bf16_t* hbuf  = (bf16_t*)alloc((size_t)M_ * C_ * 2);
  bf16_t* qkvb  = (bf16_t*)alloc((size_t)M_ * 3 * C_ * 2);
  bf16_t* qhb   = (bf16_t*)alloc((size_t)M_ * C_ * 2);
  bf16_t* khb   = (bf16_t*)alloc((size_t)M_ * C_ * 2);
  bf16_t* vTb   = (bf16_t*)alloc((size_t)M_ * C_ * 2);
  bf16_t* attnb = (bf16_t*)alloc((size_t)M_ * C_ * 2);
  bf16_t* midb  = (bf16_t*)alloc((size_t)M_ * 4 * C_ * 2);
  bf16_t* qkvwT = (bf16_t*)alloc((size_t)3 * C_ * C_ * 2);
  bf16_t* owT   = (bf16_t*)alloc((size_t)C_ * C_ * 2);
  bf16_t* fc1wT = (bf16_t*)alloc((size_t)4 * C_ * C_ * 2);
  bf16_t* fc2wT = (bf16_t*)alloc((size_t)4 * C_ * C_ * 2);
  bf16_t* headwT= (bf16_t*)alloc((size_t)C_ * V_ * 2);

  k_embed<<<M_, 256, 0, stream>>>(idx, tok_emb, pos_emb, x);
  k_transpose_bf16<<<dim3(V_ / 32, C_ / 32), 256, 0, stream>>>(head_w, headwT, C_, V_);

  for (int l = 0; l < L_; l++) {
    k_transpose_bf16<<<dim3(3 * C_ / 32, C_ / 32), 256, 0, stream>>>(
        qkv_w + (size_t)l * C_ * 3 * C_, qkvwT, C_, 3 * C_);
    k_transpose_bf16<<<dim3(C_ / 32, C_ / 32), 256, 0, stream>>>(
        attn_out_w + (size_t)l * C_ * C_, owT, C_, C_);
    k_transpose_bf16<<<dim3(4 * C_ / 32, C_ / 32), 256, 0, stream>>>(
        fc1_w + (size_t)l * C_ * 4 * C_, fc1wT, C_, 4 * C_);
    k_transpose_bf16<<<dim3(C_ / 32, 4 * C_ / 32), 256, 0, stream>>>(
        fc2_w + (size_t)l * 4 * C_ * C_, fc2wT, 4 * C_, C_);

    k_ln<<<M_, 256, 0, stream>>>(x, ln1_w + l * C_, ln1_b + l * C_, hbuf);
    k_gemm256<1, 0, 0, 0><<<dim3((3 * C_ / 256) * (M_ / 256)), 512, 0, stream>>>(
        hbuf, qkvwT, nullptr, nullptr, qkvb, M_, 3 * C_, C_);
    k_reshape_qk<<<(M_ * C_) / 256, 256, 0, stream>>>(qkvb, qhb, khb);
    k_vtrans<<<dim3(B_ * H_, T_ / 64), 256, 0, stream>>>(qkvb, vTb);
    k_attn<<<dim3(B_ * H_, T_ / 64), 256, 0, stream>>>(qhb, khb, vTb, attnb);
    k_gemm<0, 1, 0, 1><<<dim3(C_ / 128, M_ / 128), 256, 0, stream>>>(
        attnb, owT, attn_out_b + l * C_, x, x, M_, C_, C_);

    k_ln<<<M_, 256, 0, stream>>>(x, ln2_w + l * C_, ln2_b + l * C_, hbuf);
    k_gemm256<1, 1, 1, 0><<<dim3((4 * C_ / 256) * (M_ / 256)), 512, 0, stream>>>(
        hbuf, fc1wT, fc1_b + (size_t)l * 4 * C_, nullptr, midb, M_, 4 * C_, C_);
    k_gemm<0, 1, 0, 1><<<dim3(C_ / 128, M_ / 128), 256, 0, stream>>>(
        midb, fc2wT, fc2_b + l * C_, x, x, M_, C_, 4 * C_);
  }

  k_ln<<<M_, 256, 0, stream>>>(x, lnf_w, lnf_b, hbuf);
  k_gemm256<0, 0, 0, 0><<<dim3((V_ / 256) * (M_ / 256)), 512, 0, stream>>>(
      hbuf, headwT, nullptr, nullptr, out, M_, V_, C_);
}

// Round 7
// 2108.952 us; speedup vs baseline: 1.1300x; 1.0662x over previous
//
#include <hip/hip_runtime.h>
#include <cstdint>
#include <cstddef>

typedef __bf16 bf16_t;
typedef __bf16 bf16x8 __attribute__((ext_vector_type(8)));
typedef float f32x4 __attribute__((ext_vector_type(4)));
typedef int i32x4 __attribute__((ext_vector_type(4)));

#define B_ 4
#define T_ 1024
#define C_ 1024
#define H_ 16
#define L_ 6
#define V_ 32000
#define M_ (B_ * T_)   // 4096

// ---------------------------------------------------------------- embedding
__global__ __launch_bounds__(256) void k_embed(const int* __restrict__ idx,
                                               const float* __restrict__ tok,
                                               const float* __restrict__ pos,
                                               float* __restrict__ x) {
  int row = blockIdx.x;            // b*T + t
  int t = row & (T_ - 1);
  int id = idx[row];
  int c = threadIdx.x * 4;
  f32x4 a = *(const f32x4*)(tok + (size_t)id * C_ + c);
  f32x4 p = *(const f32x4*)(pos + (size_t)t * C_ + c);
  *(f32x4*)(x + (size_t)row * C_ + c) = a + p;
}

// ---------------------------------------------------------------- layernorm (f32 in -> bf16 out)
__global__ __launch_bounds__(256) void k_ln(const float* __restrict__ x,
                                            const float* __restrict__ w,
                                            const float* __restrict__ b,
                                            bf16_t* __restrict__ out) {
  __shared__ float red[8];
  int row = blockIdx.x;
  int tid = threadIdx.x;
  const float* xr = x + (size_t)row * C_;
  f32x4 v = *(const f32x4*)(xr + tid * 4);
  float s = v[0] + v[1] + v[2] + v[3];
  float q = v[0] * v[0] + v[1] * v[1] + v[2] * v[2] + v[3] * v[3];
#pragma unroll
  for (int off = 32; off; off >>= 1) {
    s += __shfl_xor(s, off);
    q += __shfl_xor(q, off);
  }
  int wid = tid >> 6;
  if ((tid & 63) == 0) { red[wid * 2] = s; red[wid * 2 + 1] = q; }
  __syncthreads();
  s = red[0] + red[2] + red[4] + red[6];
  q = red[1] + red[3] + red[5] + red[7];
  float mu = s * (1.f / C_);
  float var = q * (1.f / C_) - mu * mu;
  float rstd = rsqrtf(var + 1e-5f);
  f32x4 wv = *(const f32x4*)(w + tid * 4);
  f32x4 bv = *(const f32x4*)(b + tid * 4);
  bf16_t* o = out + (size_t)row * C_ + tid * 4;
#pragma unroll
  for (int j = 0; j < 4; j++) o[j] = (bf16_t)((v[j] - mu) * rstd * wv[j] + bv[j]);
}

// ------------------------------------------------- f32 [K][N] -> bf16 [N][K] transpose
__global__ __launch_bounds__(256) void k_transpose_bf16(const float* __restrict__ in,
                                                        bf16_t* __restrict__ out,
                                                        int K, int N) {
  __shared__ float tile[32][33];
  int n0 = blockIdx.x * 32, k0 = blockIdx.y * 32;
  int tid = threadIdx.x;
  int cr = tid >> 5, cc = tid & 31;
#pragma unroll
  for (int it = 0; it < 4; it++) {
    int r = it * 8 + cr;
    tile[r][cc] = in[(size_t)(k0 + r) * N + n0 + cc];
  }
  __syncthreads();
#pragma unroll
  for (int it = 0; it < 4; it++) {
    int r = it * 8 + cr;                       // local n
    out[(size_t)(n0 + r) * K + k0 + cc] = (bf16_t)tile[cc][r];
  }
}

// ------------------------------------------------- split qkv -> q (scaled), k in [B][H][T][D]
__global__ __launch_bounds__(256) void k_reshape_qk(const bf16_t* __restrict__ qkv,
                                                    bf16_t* __restrict__ qh,
                                                    bf16_t* __restrict__ kh) {
  int g = blockIdx.x * 256 + threadIdx.x;      // ((b*H+h)*T + t)*64 + d
  int d = g & 63;
  int t = (g >> 6) & (T_ - 1);
  int h = (g >> 16) & (H_ - 1);
  int b = g >> 20;
  size_t src = ((size_t)(b * T_ + t)) * (3 * C_) + h * 64 + d;
  qh[g] = (bf16_t)((float)qkv[src] * 0.125f);  // 1/sqrt(64), exact pow2
  kh[g] = qkv[src + C_];
}

// ------------------------------------------------- v -> vT [B][H][D][T]
__global__ __launch_bounds__(256) void k_vtrans(const bf16_t* __restrict__ qkv,
                                                bf16_t* __restrict__ vT) {
  __shared__ bf16_t tile[64][65];
  int bh = blockIdx.x;
  int t0 = blockIdx.y * 64;
  int tid = threadIdx.x;
  int c = tid & 63, rr = tid >> 6;
  int b = bh >> 4, h = bh & (H_ - 1);
  const bf16_t* src = qkv + ((size_t)(b * T_ + t0)) * (3 * C_) + 2 * C_ + h * 64;
#pragma unroll
  for (int it = 0; it < 16; it++) {
    int r = it * 4 + rr;
    tile[r][c] = src[(size_t)r * (3 * C_) + c];
  }
  __syncthreads();
  bf16_t* dst = vT + (size_t)bh * 64 * T_ + t0;
#pragma unroll
  for (int it = 0; it < 16; it++) {
    int dr = it * 4 + rr;                      // d
    dst[(size_t)dr * T_ + c] = tile[c][dr];
  }
}

// ---------------------------------------------------------------- flash attention
__global__ __launch_bounds__(256) void k_attn(const bf16_t* __restrict__ qh,
                                              const bf16_t* __restrict__ kh,
                                              const bf16_t* __restrict__ vT,
                                              bf16_t* __restrict__ outb) {
  __shared__ bf16_t p_lds[4][16 * 32];
  int tid = threadIdx.x, lane = tid & 63, wid = tid >> 6;
  int bh = blockIdx.x;
  int b = bh >> 4, h = bh & (H_ - 1);
  int qbase = blockIdx.y * 64 + wid * 16;
  const bf16_t* qp = qh + ((size_t)bh * T_ + qbase) * 64;
  const bf16_t* kp = kh + (size_t)bh * T_ * 64;
  const bf16_t* vp = vT + (size_t)bh * 64 * T_;
  int r = lane & 15, g = lane >> 4;

  bf16x8 qf0 = *(const bf16x8*)(qp + r * 64 + g * 8);
  bf16x8 qf1 = *(const bf16x8*)(qp + r * 64 + 32 + g * 8);

  f32x4 o[4];
  float m[4], l[4];
#pragma unroll
  for (int j = 0; j < 4; j++) { m[j] = -1e30f; l[j] = 0.f; o[j] = (f32x4){0.f, 0.f, 0.f, 0.f}; }

  int kv_end = qbase + 16;
  for (int jb = 0; jb < kv_end; jb += 32) {
    f32x4 s0 = (f32x4){0.f, 0.f, 0.f, 0.f};
    f32x4 s1 = (f32x4){0.f, 0.f, 0.f, 0.f};
    const bf16_t* kb0 = kp + (size_t)(jb + r) * 64 + g * 8;
    const bf16_t* kb1 = kb0 + 16 * 64;
    s0 = __builtin_amdgcn_mfma_f32_16x16x32_bf16(qf0, *(const bf16x8*)(kb0), s0, 0, 0, 0);
    s0 = __builtin_amdgcn_mfma_f32_16x16x32_bf16(qf1, *(const bf16x8*)(kb0 + 32), s0, 0, 0, 0);
    s1 = __builtin_amdgcn_mfma_f32_16x16x32_bf16(qf0, *(const bf16x8*)(kb1), s1, 0, 0, 0);
    s1 = __builtin_amdgcn_mfma_f32_16x16x32_bf16(qf1, *(const bf16x8*)(kb1 + 32), s1, 0, 0, 0);

    float p0[4], p1[4], fac[4];
#pragma unroll
    for (int j = 0; j < 4; j++) {
      int rowg = qbase + g * 4 + j;
      float v0 = s0[j], v1 = s1[j];
      if (jb + r > rowg) v0 = -1e30f;
      if (jb + 16 + r > rowg) v1 = -1e30f;
      float t = fmaxf(v0, v1);
      t = fmaxf(t, __shfl_xor(t, 1));
      t = fmaxf(t, __shfl_xor(t, 2));
      t = fmaxf(t, __shfl_xor(t, 4));
      t = fmaxf(t, __shfl_xor(t, 8));
      float nm = fmaxf(m[j], t);
      p0[j] = __expf(v0 - nm);
      p1[j] = __expf(v1 - nm);
      float f = __expf(m[j] - nm);
      float ts = p0[j] + p1[j];
      ts += __shfl_xor(ts, 1);
      ts += __shfl_xor(ts, 2);
      ts += __shfl_xor(ts, 4);
      ts += __shfl_xor(ts, 8);
      l[j] = l[j] * f + ts;
      m[j] = nm;
      fac[j] = f;
    }
    f32x4 fv = (f32x4){fac[0], fac[1], fac[2], fac[3]};
#pragma unroll
    for (int d = 0; d < 4; d++) o[d] *= fv;

    bf16_t* pl = p_lds[wid];
#pragma unroll
    for (int j = 0; j < 4; j++) {
      pl[(g * 4 + j) * 32 + r] = (bf16_t)p0[j];
      pl[(g * 4 + j) * 32 + 16 + r] = (bf16_t)p1[j];
    }
    bf16x8 pa = *(const bf16x8*)(pl + r * 32 + g * 8);
#pragma unroll
    for (int d = 0; d < 4; d++) {
      const bf16_t* vf = vp + (size_t)(d * 16 + r) * T_ + jb + g * 8;
      o[d] = __builtin_amdgcn_mfma_f32_16x16x32_bf16(pa, *(const bf16x8*)(vf), o[d], 0, 0, 0);
    }
  }

#pragma unroll
  for (int d = 0; d < 4; d++) {
#pragma unroll
    for (int j = 0; j < 4; j++) {
      float val = o[d][j] / l[j];
      outb[((size_t)(b * T_ + qbase + g * 4 + j)) * C_ + h * 64 + d * 16 + r] = (bf16_t)val;
    }
  }
}

// ---------------------------------------------------------------- shared helpers
__device__ __forceinline__ void gld_lds16(const bf16_t* g, bf16_t* l) {
  __builtin_amdgcn_global_load_lds((const __attribute__((address_space(1))) void*)g,
                                   (__attribute__((address_space(3))) void*)l, 16, 0, 0);
}
__device__ __forceinline__ bf16x8 lds_rd128(uint32_t addr) {
  i32x4 d;
  asm volatile("ds_read_b128 %0, %1" : "=v"(d) : "v"(addr));
  return __builtin_bit_cast(bf16x8, d);
}
#define BAR_() __builtin_amdgcn_s_barrier()
#define SCHED0_() __builtin_amdgcn_sched_barrier(0)
#define WLGN_(n)                                                           \
  do {                                                                     \
    asm volatile("s_waitcnt lgkmcnt(" #n ")" ::: "memory");                \
    SCHED0_();                                                             \
  } while (0)

// ---------------------------------------------------------------- 128x128 pipelined GEMM
// BK=64, LDS 64 KB (-> 2 blocks/CU), 4 waves (2Mx2N), per-wave 64x64 out.
// 3-bit XOR swizzle (phys = row*128 + (intra ^ ((row&7)<<4))), both-sides.
// R6-proven body: issue all 16 ds_reads, lgkmcnt(8), MFMA half0 overlaps half1
// reads; one vmcnt(0)+barrier per K-tile. Cross-block overlap at 2 blocks/CU.
template <int OUTBF, int HASB, int HASRELU, int HASRES>
__global__ __launch_bounds__(256, 2) void k_gemm(const bf16_t* __restrict__ A,
                                                 const bf16_t* __restrict__ Bt,
                                                 const float* __restrict__ bias,
                                                 const float* resid,
                                                 void* Cout, int M, int N, int K) {
  __shared__ bf16_t As[2][128][64];
  __shared__ bf16_t Bs[2][128][64];
  bf16_t* AsF = &As[0][0][0];
  bf16_t* BsF = &Bs[0][0][0];
  const uint32_t asb = (uint32_t)(uintptr_t)AsF;
  const uint32_t bsb = (uint32_t)(uintptr_t)BsF;

  int tid = threadIdx.x, lane = tid & 63, w = tid >> 6;
  int wr = w >> 1, wc = w & 1;
  int r15 = lane & 15, g4 = lane >> 4;

  // XCD-bijective swizzle, col-major (consecutive blocks on an XCD share B panel)
  int nwg = (int)(gridDim.x * gridDim.y);
  int bid = (int)(blockIdx.y * gridDim.x + blockIdx.x);
  int xcd = bid & 7, loc = bid >> 3;
  int q8 = nwg >> 3, r8 = nwg & 7;
  int swz = (xcd < r8) ? xcd * (q8 + 1) + loc : r8 * (q8 + 1) + (xcd - r8) * q8 + loc;
  int nY = M >> 7;
  int by = swz % nY, bx = swz / nY;
  size_t rowBase = (size_t)by * 128;
  size_t colBase = (size_t)bx * 128;

  // stage: linear LDS dest; global source col pre-applies inverse 3-bit XOR
  int srowL = (lane >> 3);                     // 0..7 within the wave's 8-row chunk
  int scol = ((lane & 7) ^ srowL) * 8;         // element col, inverse-swizzled

  // read-side: row-base + intra-row offset XOR'd with (row&7)<<4
  uint32_t xm = (uint32_t)((r15 & 7) << 4);
  uint32_t offK0 = ((uint32_t)(g4 * 16)) ^ xm;
  uint32_t offK1 = ((uint32_t)(g4 * 16 + 64)) ^ xm;
  uint32_t aRd = asb + (uint32_t)((wr * 64 + r15) * 128);
  uint32_t bRd = bsb + (uint32_t)((wc * 64 + r15) * 128);

  f32x4 acc[4][4];
#pragma unroll
  for (int i = 0; i < 4; i++)
#pragma unroll
    for (int j = 0; j < 4; j++) acc[i][j] = (f32x4){0.f, 0.f, 0.f, 0.f};

  bf16x8 a0[4], a1[4], b0[4], b1[4];

#define KSTAGE_(tk, bufv)                                                            \
  do {                                                                               \
    _Pragma("unroll") for (int _q = 0; _q < 4; _q++) {                               \
      int _row = _q * 32 + w * 8 + srowL;                                            \
      const bf16_t* _ga = A + (rowBase + _row) * (size_t)K + (size_t)(tk)*64 + scol; \
      const bf16_t* _gb = Bt + (colBase + _row) * (size_t)K + (size_t)(tk)*64 + scol;\
      gld_lds16(_ga, AsF + (bufv)*8192 + _q * 2048 + w * 512);                       \
      gld_lds16(_gb, BsF + (bufv)*8192 + _q * 2048 + w * 512);                       \
    }                                                                                \
  } while (0)

#define KRDS_(aset, bset, kk, bufv)                                                  \
  do {                                                                               \
    uint32_t _off = (kk) ? offK1 : offK0;                                            \
    uint32_t _ab = aRd + (uint32_t)(bufv)*16384u + _off;                             \
    uint32_t _bb = bRd + (uint32_t)(bufv)*16384u + _off;                             \
    _Pragma("unroll") for (int _m = 0; _m < 4; _m++)                                 \
        aset[_m] = lds_rd128(_ab + _m * 2048);                                       \
    _Pragma("unroll") for (int _n = 0; _n < 4; _n++)                                 \
        bset[_n] = lds_rd128(_bb + _n * 2048);                                       \
  } while (0)

#define KMFH_(aset, bset)                                                            \
  do {                                                                               \
    __builtin_amdgcn_s_setprio(1);                                                   \
    _Pragma("unroll") for (int _m = 0; _m < 4; _m++)                                 \
        _Pragma("unroll") for (int _n = 0; _n < 4; _n++)                             \
            acc[_m][_n] = __builtin_amdgcn_mfma_f32_16x16x32_bf16(                   \
                aset[_m], bset[_n], acc[_m][_n], 0, 0, 0);                           \
    __builtin_amdgcn_s_setprio(0);                                                   \
  } while (0)

  // prologue: stage tile 0
  KSTAGE_(0, 0);
  asm volatile("s_waitcnt vmcnt(0)" ::: "memory");
  BAR_();

  int NT = K >> 6;
  for (int kt = 0; kt < NT; ++kt) {
    int buf = kt & 1;
    bool pf = (kt + 1 < NT);
    if (pf) KSTAGE_(kt + 1, buf ^ 1);
    KRDS_(a0, b0, 0, buf);
    KRDS_(a1, b1, 1, buf);
    WLGN_(8);                  // half0 frags ready
    KMFH_(a0, b0);
    WLGN_(0);                  // half1 frags ready (landed under MFMA)
    KMFH_(a1, b1);
    asm volatile("s_waitcnt vmcnt(0)" ::: "memory");
    BAR_();
  }

#pragma unroll
  for (int i = 0; i < 4; i++) {
    size_t row0 = rowBase + wr * 64 + i * 16 + g4 * 4;
#pragma unroll
    for (int j = 0; j < 4; j++) {
      size_t col = colBase + wc * 64 + j * 16 + r15;
      float bi = HASB ? bias[col] : 0.f;
#pragma unroll
      for (int q = 0; q < 4; q++) {
        size_t row = row0 + q;
        float v = acc[i][j][q] + bi;
        if (HASRELU) v = fmaxf(v, 0.f);
        if (HASRES) v += resid[row * (size_t)N + col];
        if (OUTBF)
          ((bf16_t*)Cout)[row * (size_t)N + col] = (bf16_t)v;
        else
          ((float*)Cout)[row * (size_t)N + col] = v;
      }
    }
  }
#undef KSTAGE_
#undef KRDS_
#undef KMFH_
}

// ---------------------------------------------------------------- 256x256 pipelined GEMM (head)
#define STAGE_(q, tk, bufv)                                                           \
  do {                                                                                \
    const bf16_t* _ga = A + (size_t)(rowBase + (q)*64 + srow) * (size_t)K +           \
                        (size_t)(tk)*64 + scol;                                       \
    const bf16_t* _gb = Bt + (size_t)(colBase + (q)*64 + srow) * (size_t)K +          \
                        (size_t)(tk)*64 + scol;                                       \
    gld_lds16(_ga, AsF + (bufv)*16384 + (q)*4096 + w * 512);                          \
    gld_lds16(_gb, BsF + (bufv)*16384 + (q)*4096 + w * 512);                          \
  } while (0)

#define RDS_(aset, bset, kk, bufv)                                                    \
  do {                                                                                \
    uint32_t _off = (kk) ? offK1 : offK0;                                             \
    uint32_t _ab = aRd + (uint32_t)(bufv)*32768u + _off;                              \
    uint32_t _bb = bRd + (uint32_t)(bufv)*32768u + _off;                              \
    _Pragma("unroll") for (int _m = 0; _m < 8; _m++)                                  \
        aset[_m] = lds_rd128(_ab + _m * 2048);                                        \
    _Pragma("unroll") for (int _n = 0; _n < 4; _n++)                                  \
        bset[_n] = lds_rd128(_bb + _n * 2048);                                        \
  } while (0)

#define MFH_(aset, bset)                                                              \
  do {                                                                                \
    __builtin_amdgcn_s_setprio(1);                                                    \
    _Pragma("unroll") for (int _m = 0; _m < 8; _m++)                                  \
        _Pragma("unroll") for (int _n = 0; _n < 4; _n++)                              \
            acc[_m][_n] = __builtin_amdgcn_mfma_f32_16x16x32_bf16(                    \
                aset[_m], bset[_n], acc[_m][_n], 0, 0, 0);                            \
    __builtin_amdgcn_s_setprio(0);                                                    \
  } while (0)

template <int OUTBF, int HASB, int HASRELU, int HASRES>
__global__ __launch_bounds__(512, 2) void k_gemm256(const bf16_t* __restrict__ A,
                                                    const bf16_t* __restrict__ Bt,
                                                    const float* __restrict__ bias,
                                                    const float* resid,
                                                    void* Cout, int M, int N, int K) {
  __shared__ bf16_t As[2][256][64];
  __shared__ bf16_t Bs[2][256][64];
  bf16_t* AsF = &As[0][0][0];
  bf16_t* BsF = &Bs[0][0][0];
  const uint32_t asb = (uint32_t)(uintptr_t)AsF;
  const uint32_t bsb = (uint32_t)(uintptr_t)BsF;

  int tid = threadIdx.x, lane = tid & 63, w = tid >> 6;
  int wr = w >> 2, wc = w & 3;
  int r15 = lane & 15, g4 = lane >> 4;

  int nwg = (int)gridDim.x;
  int bid = (int)blockIdx.x;
  int xcd = bid & 7, loc = bid >> 3;
  int q8 = nwg >> 3, r8 = nwg & 7;
  int swz = (xcd < r8) ? xcd * (q8 + 1) + loc : r8 * (q8 + 1) + (xcd - r8) * q8 + loc;
  int nY = M >> 8;
  int by = swz % nY, bx = swz / nY;
  int rowBase = by * 256, colBase = bx * 256;

  int srow = w * 8 + (lane >> 3);
  int scol = ((lane & 7) ^ (lane >> 3)) * 8;

  uint32_t xm = (uint32_t)((r15 & 7) << 4);
  uint32_t offK0 = ((uint32_t)(g4 * 16)) ^ xm;
  uint32_t offK1 = ((uint32_t)(g4 * 16 + 64)) ^ xm;
  uint32_t aRd = asb + (uint32_t)((wr * 128 + r15) * 128);
  uint32_t bRd = bsb + (uint32_t)((wc * 64 + r15) * 128);

  f32x4 acc[8][4];
#pragma unroll
  for (int i = 0; i < 8; i++)
#pragma unroll
    for (int j = 0; j < 4; j++) acc[i][j] = (f32x4){0.f, 0.f, 0.f, 0.f};

  bf16x8 a0[8], a1[8], b0[4], b1[4];

#pragma unroll
  for (int q = 0; q < 4; q++) STAGE_(q, 0, 0);
  asm volatile("s_waitcnt vmcnt(0)" ::: "memory");
  BAR_();

  int NT = K >> 6;
  for (int kt = 0; kt < NT; ++kt) {
    int buf = kt & 1;
    bool pf = (kt + 1 < NT);
    if (pf) {
#pragma unroll
      for (int q = 0; q < 4; q++) STAGE_(q, kt + 1, buf ^ 1);
    }
    RDS_(a0, b0, 0, buf);
    RDS_(a1, b1, 1, buf);
    WLGN_(12);
    MFH_(a0, b0);
    WLGN_(0);
    MFH_(a1, b1);
    asm volatile("s_waitcnt vmcnt(0)" ::: "memory");
    BAR_();
  }

#pragma unroll
  for (int m = 0; m < 8; m++) {
    size_t row0 = (size_t)rowBase + wr * 128 + m * 16 + g4 * 4;
#pragma unroll
    for (int n = 0; n < 4; n++) {
      size_t col = (size_t)colBase + wc * 64 + n * 16 + r15;
      float bi = HASB ? bias[col] : 0.f;
#pragma unroll
      for (int qq = 0; qq < 4; qq++) {
        size_t row = row0 + qq;
        float v = acc[m][n][qq] + bi;
        if (HASRELU) v = fmaxf(v, 0.f);
        if (HASRES) v += resid[row * (size_t)N + col];
        if (OUTBF)
          ((bf16_t*)Cout)[row * (size_t)N + col] = (bf16_t)v;
        else
          ((float*)Cout)[row * (size_t)N + col] = v;
      }
    }
  }
}

// ---------------------------------------------------------------- launch
extern "C" void kernel_launch(void* const* d_in, const int* in_sizes, int n_in,
                              void* d_out, int out_size, void* d_ws, size_t ws_size,
                              hipStream_t stream) {
  (void)in_sizes; (void)n_in; (void)out_size; (void)ws_size;
  const int* idx = (const int*)d_in[0];
  const float* tok_emb = (const float*)d_in[1];
  const float* pos_emb = (const float*)d_in[2];
  const float* qkv_w = (const float*)d_in[3];
  const float* attn_out_w = (const float*)d_in[4];
  const float* attn_out_b = (const float*)d_in[5];
  const float* fc1_w = (const float*)d_in[6];
  const float* fc1_b = (const float*)d_in[7];
  const float* fc2_w = (const float*)d_in[8];
  const float* fc2_b = (const float*)d_in[9];
  const float* ln1_w = (const float*)d_in[10];
  const float* ln1_b = (const float*)d_in[11];
  const float* ln2_w = (const float*)d_in[12];
  const float* ln2_b = (const float*)d_in[13];
  const float* lnf_w = (const float*)d_in[14];
  const float* lnf_b = (const float*)d_in[15];
  const float* head_w = (const float*)d_in[16];
  float* out = (float*)d_out;

  char* wsp = (char*)d_ws;
  auto alloc = [&](size_t bytes) {
    char* p = wsp;
    wsp += (bytes + 255) & ~(size_t)255;
    return p;
  };
  float* x      = (float*)alloc((size_t)M_ * C_ * 4);
  bf16_t* hbuf  = (bf16_t*)alloc((size_t)M_ * C_ * 2);
  bf16_t* qkvb  = (bf16_t*)alloc((size_t)M_ * 3 * C_ * 2);
  bf16_t* qhb   = (bf16_t*)alloc((size_t)M_ * C_ * 2);
  bf16_t* khb   = (bf16_t*)alloc((size_t)M_ * C_ * 2);
  bf16_t* vTb   = (bf16_t*)alloc((size_t)M_ * C_ * 2);
  bf16_t* attnb = (bf16_t*)alloc((size_t)M_ * C_ * 2);
  bf16_t* midb  = (bf16_t*)alloc((size_t)M_ * 4 * C_ * 2);
  bf16_t* qkvwT = (bf16_t*)alloc((size_t)3 * C_ * C_ * 2);
  bf16_t* owT   = (bf16_t*)alloc((size_t)C_ * C_ * 2);
  bf16_t* fc1wT = (bf16_t*)alloc((size_t)4 * C_ * C_ * 2);
  bf16_t* fc2wT = (bf16_t*)alloc((size_t)4 * C_ * C_ * 2);
  bf16_t* headwT= (bf16_t*)alloc((size_t)C_ * V_ * 2);

  k_embed<<<M_, 256, 0, stream>>>(idx, tok_emb, pos_emb, x);
  k_transpose_bf16<<<dim3(V_ / 32, C_ / 32), 256, 0, stream>>>(head_w, headwT, C_, V_);

  for (int l = 0; l < L_; l++) {
    k_transpose_bf16<<<dim3(3 * C_ / 32, C_ / 32), 256, 0, stream>>>(
        qkv_w + (size_t)l * C_ * 3 * C_, qkvwT, C_, 3 * C_);
    k_transpose_bf16<<<dim3(C_ / 32, C_ / 32), 256, 0, stream>>>(
        attn_out_w + (size_t)l * C_ * C_, owT, C_, C_);
    k_transpose_bf16<<<dim3(4 * C_ / 32, C_ / 32), 256, 0, stream>>>(
        fc1_w + (size_t)l * C_ * 4 * C_, fc1wT, C_, 4 * C_);
    k_transpose_bf16<<<dim3(C_ / 32, 4 * C_ / 32), 256, 0, stream>>>(
        fc2_w + (size_t)l * 4 * C_ * C_, fc2wT, 4 * C_, C_);

    k_ln<<<M_, 256, 0, stream>>>(x, ln1_w + l * C_, ln1_b + l * C_, hbuf);
    k_gemm<1, 0, 0, 0><<<dim3(3 * C_ / 128, M_ / 128), 256, 0, stream>>>(
        hbuf, qkvwT, nullptr, nullptr, qkvb, M_, 3 * C_, C_);
    k_reshape_qk<<<(M_ * C_) / 256, 256, 0, stream>>>(qkvb, qhb, khb);
    k_vtrans<<<dim3(B_ * H_, T_ / 64), 256, 0, stream>>>(qkvb, vTb);
    k_attn<<<dim3(B_ * H_, T_ / 64), 256, 0, stream>>>(qhb, khb, vTb, attnb);
    k_gemm<0, 1, 0, 1><<<dim3(C_ / 128, M_ / 128), 256, 0, stream>>>(
        attnb, owT, attn_out_b + l * C_, x, x, M_, C_, C_);

    k_ln<<<M_, 256, 0, stream>>>(x, ln2_w + l * C_, ln2_b + l * C_, hbuf);
    k_gemm<1, 1, 1, 0><<<dim3(4 * C_ / 128, M_ / 128), 256, 0, stream>>>(
        hbuf, fc1wT, fc1_b + (size_t)l * 4 * C_, nullptr, midb, M_, 4 * C_, C_);
    k_gemm<0, 1, 0, 1><<<dim3(C_ / 128, M_ / 128), 256, 0, stream>>>(
        midb, fc2wT, fc2_b + l * C_, x, x, M_, C_, 4 * C_);
  }

  k_ln<<<M_, 256, 0, stream>>>(x, lnf_w, lnf_b, hbuf);
  k_gemm256<0, 0, 0, 0><<<dim3((V_ / 256) * (M_ / 256)), 512, 0, stream>>>(
      hbuf, headwT, nullptr, nullptr, out, M_, V_, C_);
}

// Round 8
// 2055.679 us; speedup vs baseline: 1.1593x; 1.0259x over previous
//
#include <hip/hip_runtime.h>
#include <cstdint>
#include <cstddef>

typedef __bf16 bf16_t;
typedef __bf16 bf16x8 __attribute__((ext_vector_type(8)));
typedef float f32x4 __attribute__((ext_vector_type(4)));
typedef int i32x4 __attribute__((ext_vector_type(4)));

#define B_ 4
#define T_ 1024
#define C_ 1024
#define H_ 16
#define L_ 6
#define V_ 32000
#define M_ (B_ * T_)   // 4096

// ---------------------------------------------------------------- embedding
__global__ __launch_bounds__(256) void k_embed(const int* __restrict__ idx,
                                               const float* __restrict__ tok,
                                               const float* __restrict__ pos,
                                               float* __restrict__ x) {
  int row = blockIdx.x;            // b*T + t
  int t = row & (T_ - 1);
  int id = idx[row];
  int c = threadIdx.x * 4;
  f32x4 a = *(const f32x4*)(tok + (size_t)id * C_ + c);
  f32x4 p = *(const f32x4*)(pos + (size_t)t * C_ + c);
  *(f32x4*)(x + (size_t)row * C_ + c) = a + p;
}

// ---------------------------------------------------------------- layernorm (f32 in -> bf16 out)
__global__ __launch_bounds__(256) void k_ln(const float* __restrict__ x,
                                            const float* __restrict__ w,
                                            const float* __restrict__ b,
                                            bf16_t* __restrict__ out) {
  __shared__ float red[8];
  int row = blockIdx.x;
  int tid = threadIdx.x;
  const float* xr = x + (size_t)row * C_;
  f32x4 v = *(const f32x4*)(xr + tid * 4);
  float s = v[0] + v[1] + v[2] + v[3];
  float q = v[0] * v[0] + v[1] * v[1] + v[2] * v[2] + v[3] * v[3];
#pragma unroll
  for (int off = 32; off; off >>= 1) {
    s += __shfl_xor(s, off);
    q += __shfl_xor(q, off);
  }
  int wid = tid >> 6;
  if ((tid & 63) == 0) { red[wid * 2] = s; red[wid * 2 + 1] = q; }
  __syncthreads();
  s = red[0] + red[2] + red[4] + red[6];
  q = red[1] + red[3] + red[5] + red[7];
  float mu = s * (1.f / C_);
  float var = q * (1.f / C_) - mu * mu;
  float rstd = rsqrtf(var + 1e-5f);
  f32x4 wv = *(const f32x4*)(w + tid * 4);
  f32x4 bv = *(const f32x4*)(b + tid * 4);
  bf16_t* o = out + (size_t)row * C_ + tid * 4;
#pragma unroll
  for (int j = 0; j < 4; j++) o[j] = (bf16_t)((v[j] - mu) * rstd * wv[j] + bv[j]);
}

// ------------------------------------------------- head transpose f32 [K][N] -> bf16 [N][K]
__global__ __launch_bounds__(256) void k_transpose_bf16(const float* __restrict__ in,
                                                        bf16_t* __restrict__ out,
                                                        int K, int N) {
  __shared__ float tile[32][33];
  int n0 = blockIdx.x * 32, k0 = blockIdx.y * 32;
  int tid = threadIdx.x;
  int cr = tid >> 5, cc = tid & 31;
#pragma unroll
  for (int it = 0; it < 4; it++) {
    int r = it * 8 + cr;
    tile[r][cc] = in[(size_t)(k0 + r) * N + n0 + cc];
  }
  __syncthreads();
#pragma unroll
  for (int it = 0; it < 4; it++) {
    int r = it * 8 + cr;                       // local n
    out[(size_t)(n0 + r) * K + k0 + cc] = (bf16_t)tile[cc][r];
  }
}

// ------------------------------------------------- fused per-layer weight transpose
// one dispatch handles qkv (q cols scaled by 0.125), attn_out, fc1, fc2.
// tile ranges: [0,3072) qkv | [3072,4096) attn | [4096,8192) fc1 | [8192,12288) fc2
__global__ __launch_bounds__(256) void k_transpose_layer(
    const float* __restrict__ qkvw, const float* __restrict__ attnw,
    const float* __restrict__ fc1w, const float* __restrict__ fc2w,
    bf16_t* __restrict__ qkvT, bf16_t* __restrict__ owT,
    bf16_t* __restrict__ fc1T, bf16_t* __restrict__ fc2T) {
  __shared__ float tile[32][33];
  int tb = blockIdx.x;
  const float* in;
  bf16_t* out;
  int K, N;
  bool qs = false;
  if (tb < 3072) { in = qkvw; out = qkvT; K = 1024; N = 3072; qs = true; }
  else if (tb < 4096) { tb -= 3072; in = attnw; out = owT; K = 1024; N = 1024; }
  else if (tb < 8192) { tb -= 4096; in = fc1w; out = fc1T; K = 1024; N = 4096; }
  else { tb -= 8192; in = fc2w; out = fc2T; K = 4096; N = 1024; }
  int nTx = N >> 5;
  int n0 = (tb % nTx) * 32, k0 = (tb / nTx) * 32;
  int tid = threadIdx.x;
  int cr = tid >> 5, cc = tid & 31;
#pragma unroll
  for (int it = 0; it < 4; it++) {
    int r = it * 8 + cr;
    tile[r][cc] = in[(size_t)(k0 + r) * N + n0 + cc];
  }
  __syncthreads();
#pragma unroll
  for (int it = 0; it < 4; it++) {
    int r = it * 8 + cr;                       // local n
    float v = tile[cc][r];
    if (qs && (n0 + r) < 1024) v *= 0.125f;    // fold 1/sqrt(D) into Wq
    out[(size_t)(n0 + r) * K + k0 + cc] = (bf16_t)v;
  }
}

// ------------------------------------------------- v [bh][t][d] -> vT [bh][d][t]
__global__ __launch_bounds__(256) void k_vtrans(const bf16_t* __restrict__ vh,
                                                bf16_t* __restrict__ vT) {
  __shared__ bf16_t tile[64][65];
  int bh = blockIdx.x;
  int t0 = blockIdx.y * 64;
  int tid = threadIdx.x;
  int c = tid & 63, rr = tid >> 6;
  const bf16_t* src = vh + ((size_t)bh * T_ + t0) * 64;
#pragma unroll
  for (int it = 0; it < 16; it++) {
    int r = it * 4 + rr;
    tile[r][c] = src[(size_t)r * 64 + c];
  }
  __syncthreads();
  bf16_t* dst = vT + (size_t)bh * 64 * T_ + t0;
#pragma unroll
  for (int it = 0; it < 16; it++) {
    int dr = it * 4 + rr;                      // d
    dst[(size_t)dr * T_ + c] = tile[c][dr];
  }
}

// ---------------------------------------------------------------- flash attention
__global__ __launch_bounds__(256) void k_attn(const bf16_t* __restrict__ qh,
                                              const bf16_t* __restrict__ kh,
                                              const bf16_t* __restrict__ vT,
                                              bf16_t* __restrict__ outb) {
  __shared__ bf16_t p_lds[4][16 * 32];
  int tid = threadIdx.x, lane = tid & 63, wid = tid >> 6;
  int bh = blockIdx.x;
  int b = bh >> 4, h = bh & (H_ - 1);
  int qbase = blockIdx.y * 64 + wid * 16;
  const bf16_t* qp = qh + ((size_t)bh * T_ + qbase) * 64;
  const bf16_t* kp = kh + (size_t)bh * T_ * 64;
  const bf16_t* vp = vT + (size_t)bh * 64 * T_;
  int r = lane & 15, g = lane >> 4;

  bf16x8 qf0 = *(const bf16x8*)(qp + r * 64 + g * 8);
  bf16x8 qf1 = *(const bf16x8*)(qp + r * 64 + 32 + g * 8);

  f32x4 o[4];
  float m[4], l[4];
#pragma unroll
  for (int j = 0; j < 4; j++) { m[j] = -1e30f; l[j] = 0.f; o[j] = (f32x4){0.f, 0.f, 0.f, 0.f}; }

  int kv_end = qbase + 16;
  for (int jb = 0; jb < kv_end; jb += 32) {
    f32x4 s0 = (f32x4){0.f, 0.f, 0.f, 0.f};
    f32x4 s1 = (f32x4){0.f, 0.f, 0.f, 0.f};
    const bf16_t* kb0 = kp + (size_t)(jb + r) * 64 + g * 8;
    const bf16_t* kb1 = kb0 + 16 * 64;
    s0 = __builtin_amdgcn_mfma_f32_16x16x32_bf16(qf0, *(const bf16x8*)(kb0), s0, 0, 0, 0);
    s0 = __builtin_amdgcn_mfma_f32_16x16x32_bf16(qf1, *(const bf16x8*)(kb0 + 32), s0, 0, 0, 0);
    s1 = __builtin_amdgcn_mfma_f32_16x16x32_bf16(qf0, *(const bf16x8*)(kb1), s1, 0, 0, 0);
    s1 = __builtin_amdgcn_mfma_f32_16x16x32_bf16(qf1, *(const bf16x8*)(kb1 + 32), s1, 0, 0, 0);

    float p0[4], p1[4], fac[4];
#pragma unroll
    for (int j = 0; j < 4; j++) {
      int rowg = qbase + g * 4 + j;
      float v0 = s0[j], v1 = s1[j];
      if (jb + r > rowg) v0 = -1e30f;
      if (jb + 16 + r > rowg) v1 = -1e30f;
      float t = fmaxf(v0, v1);
      t = fmaxf(t, __shfl_xor(t, 1));
      t = fmaxf(t, __shfl_xor(t, 2));
      t = fmaxf(t, __shfl_xor(t, 4));
      t = fmaxf(t, __shfl_xor(t, 8));
      float nm = fmaxf(m[j], t);
      p0[j] = __expf(v0 - nm);
      p1[j] = __expf(v1 - nm);
      float f = __expf(m[j] - nm);
      float ts = p0[j] + p1[j];
      ts += __shfl_xor(ts, 1);
      ts += __shfl_xor(ts, 2);
      ts += __shfl_xor(ts, 4);
      ts += __shfl_xor(ts, 8);
      l[j] = l[j] * f + ts;
      m[j] = nm;
      fac[j] = f;
    }
    f32x4 fv = (f32x4){fac[0], fac[1], fac[2], fac[3]};
#pragma unroll
    for (int d = 0; d < 4; d++) o[d] *= fv;

    bf16_t* pl = p_lds[wid];
#pragma unroll
    for (int j = 0; j < 4; j++) {
      pl[(g * 4 + j) * 32 + r] = (bf16_t)p0[j];
      pl[(g * 4 + j) * 32 + 16 + r] = (bf16_t)p1[j];
    }
    bf16x8 pa = *(const bf16x8*)(pl + r * 32 + g * 8);
#pragma unroll
    for (int d = 0; d < 4; d++) {
      const bf16_t* vf = vp + (size_t)(d * 16 + r) * T_ + jb + g * 8;
      o[d] = __builtin_amdgcn_mfma_f32_16x16x32_bf16(pa, *(const bf16x8*)(vf), o[d], 0, 0, 0);
    }
  }

#pragma unroll
  for (int d = 0; d < 4; d++) {
#pragma unroll
    for (int j = 0; j < 4; j++) {
      float val = o[d][j] / l[j];
      outb[((size_t)(b * T_ + qbase + g * 4 + j)) * C_ + h * 64 + d * 16 + r] = (bf16_t)val;
    }
  }
}

// ---------------------------------------------------------------- shared helpers
__device__ __forceinline__ void gld_lds16(const bf16_t* g, bf16_t* l) {
  __builtin_amdgcn_global_load_lds((const __attribute__((address_space(1))) void*)g,
                                   (__attribute__((address_space(3))) void*)l, 16, 0, 0);
}
__device__ __forceinline__ bf16x8 lds_rd128(uint32_t addr) {
  i32x4 d;
  asm volatile("ds_read_b128 %0, %1" : "=v"(d) : "v"(addr));
  return __builtin_bit_cast(bf16x8, d);
}
#define BAR_() __builtin_amdgcn_s_barrier()
#define SCHED0_() __builtin_amdgcn_sched_barrier(0)
#define WLGN_(n)                                                           \
  do {                                                                     \
    asm volatile("s_waitcnt lgkmcnt(" #n ")" ::: "memory");                \
    SCHED0_();                                                             \
  } while (0)

// ---------------------------------------------------------------- 128x128 pipelined GEMM
// MODE: 0 = f32 out, 1 = bf16 out, 2 = qkv-split bf16 out ([B][H][T][D] x3).
template <int MODE, int HASB, int HASRELU, int HASRES>
__global__ __launch_bounds__(256, 2) void k_gemm(const bf16_t* __restrict__ A,
                                                 const bf16_t* __restrict__ Bt,
                                                 const float* __restrict__ bias,
                                                 const float* resid,
                                                 void* Cout, int M, int N, int K) {
  __shared__ bf16_t As[2][128][64];
  __shared__ bf16_t Bs[2][128][64];
  bf16_t* AsF = &As[0][0][0];
  bf16_t* BsF = &Bs[0][0][0];
  const uint32_t asb = (uint32_t)(uintptr_t)AsF;
  const uint32_t bsb = (uint32_t)(uintptr_t)BsF;

  int tid = threadIdx.x, lane = tid & 63, w = tid >> 6;
  int wr = w >> 1, wc = w & 1;
  int r15 = lane & 15, g4 = lane >> 4;

  int nwg = (int)(gridDim.x * gridDim.y);
  int bid = (int)(blockIdx.y * gridDim.x + blockIdx.x);
  int xcd = bid & 7, loc = bid >> 3;
  int q8 = nwg >> 3, r8 = nwg & 7;
  int swz = (xcd < r8) ? xcd * (q8 + 1) + loc : r8 * (q8 + 1) + (xcd - r8) * q8 + loc;
  int nY = M >> 7;
  int by = swz % nY, bx = swz / nY;
  size_t rowBase = (size_t)by * 128;
  size_t colBase = (size_t)bx * 128;

  int srowL = (lane >> 3);
  int scol = ((lane & 7) ^ srowL) * 8;

  uint32_t xm = (uint32_t)((r15 & 7) << 4);
  uint32_t offK0 = ((uint32_t)(g4 * 16)) ^ xm;
  uint32_t offK1 = ((uint32_t)(g4 * 16 + 64)) ^ xm;
  uint32_t aRd = asb + (uint32_t)((wr * 64 + r15) * 128);
  uint32_t bRd = bsb + (uint32_t)((wc * 64 + r15) * 128);

  f32x4 acc[4][4];
#pragma unroll
  for (int i = 0; i < 4; i++)
#pragma unroll
    for (int j = 0; j < 4; j++) acc[i][j] = (f32x4){0.f, 0.f, 0.f, 0.f};

  bf16x8 a0[4], a1[4], b0[4], b1[4];

#define KSTAGE_(tk, bufv)                                                            \
  do {                                                                               \
    _Pragma("unroll") for (int _q = 0; _q < 4; _q++) {                               \
      int _row = _q * 32 + w * 8 + srowL;                                            \
      const bf16_t* _ga = A + (rowBase + _row) * (size_t)K + (size_t)(tk)*64 + scol; \
      const bf16_t* _gb = Bt + (colBase + _row) * (size_t)K + (size_t)(tk)*64 + scol;\
      gld_lds16(_ga, AsF + (bufv)*8192 + _q * 2048 + w * 512);                       \
      gld_lds16(_gb, BsF + (bufv)*8192 + _q * 2048 + w * 512);                       \
    }                                                                                \
  } while (0)

#define KRDS_(aset, bset, kk, bufv)                                                  \
  do {                                                                               \
    uint32_t _off = (kk) ? offK1 : offK0;                                            \
    uint32_t _ab = aRd + (uint32_t)(bufv)*16384u + _off;                             \
    uint32_t _bb = bRd + (uint32_t)(bufv)*16384u + _off;                             \
    _Pragma("unroll") for (int _m = 0; _m < 4; _m++)                                 \
        aset[_m] = lds_rd128(_ab + _m * 2048);                                       \
    _Pragma("unroll") for (int _n = 0; _n < 4; _n++)                                 \
        bset[_n] = lds_rd128(_bb + _n * 2048);                                       \
  } while (0)

#define KMFH_(aset, bset)                                                            \
  do {                                                                               \
    __builtin_amdgcn_s_setprio(1);                                                   \
    _Pragma("unroll") for (int _m = 0; _m < 4; _m++)                                 \
        _Pragma("unroll") for (int _n = 0; _n < 4; _n++)                             \
            acc[_m][_n] = __builtin_amdgcn_mfma_f32_16x16x32_bf16(                   \
                aset[_m], bset[_n], acc[_m][_n], 0, 0, 0);                           \
    __builtin_amdgcn_s_setprio(0);                                                   \
  } while (0)

  KSTAGE_(0, 0);
  asm volatile("s_waitcnt vmcnt(0)" ::: "memory");
  BAR_();

  int NT = K >> 6;
  for (int kt = 0; kt < NT; ++kt) {
    int buf = kt & 1;
    bool pf = (kt + 1 < NT);
    if (pf) KSTAGE_(kt + 1, buf ^ 1);
    KRDS_(a0, b0, 0, buf);
    KRDS_(a1, b1, 1, buf);
    WLGN_(8);
    KMFH_(a0, b0);
    WLGN_(0);
    KMFH_(a1, b1);
    asm volatile("s_waitcnt vmcnt(0)" ::: "memory");
    BAR_();
  }

#pragma unroll
  for (int i = 0; i < 4; i++) {
    size_t row0 = rowBase + wr * 64 + i * 16 + g4 * 4;
#pragma unroll
    for (int j = 0; j < 4; j++) {
      size_t col = colBase + wc * 64 + j * 16 + r15;
      float bi = HASB ? bias[col] : 0.f;
#pragma unroll
      for (int q = 0; q < 4; q++) {
        size_t row = row0 + q;
        float v = acc[i][j][q] + bi;
        if (HASRELU) v = fmaxf(v, 0.f);
        if (HASRES) v += resid[row * (size_t)N + col];
        if (MODE == 2) {
          int part = (int)(col >> 10);
          int within = (int)col & 1023;
          int hh = within >> 6, dd = within & 63;
          int bb = (int)(row >> 10), tt = (int)row & 1023;
          bf16_t* dstp = (bf16_t*)Cout + (size_t)part * ((size_t)M_ * C_);
          dstp[(((size_t)(bb * 16 + hh)) * 1024 + tt) * 64 + dd] = (bf16_t)v;
        } else if (MODE == 1) {
          ((bf16_t*)Cout)[row * (size_t)N + col] = (bf16_t)v;
        } else {
          ((float*)Cout)[row * (size_t)N + col] = v;
        }
      }
    }
  }
#undef KSTAGE_
#undef KRDS_
#undef KMFH_
}

// ---------------------------------------------------------------- 256x256 pipelined GEMM (head)
#define STAGE_(q, tk, bufv)                                                           \
  do {                                                                                \
    const bf16_t* _ga = A + (size_t)(rowBase + (q)*64 + srow) * (size_t)K +           \
                        (size_t)(tk)*64 + scol;                                       \
    const bf16_t* _gb = Bt + (size_t)(colBase + (q)*64 + srow) * (size_t)K +          \
                        (size_t)(tk)*64 + scol;                                       \
    gld_lds16(_ga, AsF + (bufv)*16384 + (q)*4096 + w * 512);                          \
    gld_lds16(_gb, BsF + (bufv)*16384 + (q)*4096 + w * 512);                          \
  } while (0)

#define RDS_(aset, bset, kk, bufv)                                                    \
  do {                                                                                \
    uint32_t _off = (kk) ? offK1 : offK0;                                             \
    uint32_t _ab = aRd + (uint32_t)(bufv)*32768u + _off;                              \
    uint32_t _bb = bRd + (uint32_t)(bufv)*32768u + _off;                              \
    _Pragma("unroll") for (int _m = 0; _m < 8; _m++)                                  \
        aset[_m] = lds_rd128(_ab + _m * 2048);                                        \
    _Pragma("unroll") for (int _n = 0; _n < 4; _n++)                                  \
        bset[_n] = lds_rd128(_bb + _n * 2048);                                        \
  } while (0)

#define MFH_(aset, bset)                                                              \
  do {                                                                                \
    __builtin_amdgcn_s_setprio(1);                                                    \
    _Pragma("unroll") for (int _m = 0; _m < 8; _m++)                                  \
        _Pragma("unroll") for (int _n = 0; _n < 4; _n++)                              \
            acc[_m][_n] = __builtin_amdgcn_mfma_f32_16x16x32_bf16(                    \
                aset[_m], bset[_n], acc[_m][_n], 0, 0, 0);                            \
    __builtin_amdgcn_s_setprio(0);                                                    \
  } while (0)

template <int OUTBF, int HASB, int HASRELU, int HASRES>
__global__ __launch_bounds__(512, 2) void k_gemm256(const bf16_t* __restrict__ A,
                                                    const bf16_t* __restrict__ Bt,
                                                    const float* __restrict__ bias,
                                                    const float* resid,
                                                    void* Cout, int M, int N, int K) {
  __shared__ bf16_t As[2][256][64];
  __shared__ bf16_t Bs[2][256][64];
  bf16_t* AsF = &As[0][0][0];
  bf16_t* BsF = &Bs[0][0][0];
  const uint32_t asb = (uint32_t)(uintptr_t)AsF;
  const uint32_t bsb = (uint32_t)(uintptr_t)BsF;

  int tid = threadIdx.x, lane = tid & 63, w = tid >> 6;
  int wr = w >> 2, wc = w & 3;
  int r15 = lane & 15, g4 = lane >> 4;

  int nwg = (int)gridDim.x;
  int bid = (int)blockIdx.x;
  int xcd = bid & 7, loc = bid >> 3;
  int q8 = nwg >> 3, r8 = nwg & 7;
  int swz = (xcd < r8) ? xcd * (q8 + 1) + loc : r8 * (q8 + 1) + (xcd - r8) * q8 + loc;
  int nY = M >> 8;
  int by = swz % nY, bx = swz / nY;
  int rowBase = by * 256, colBase = bx * 256;

  int srow = w * 8 + (lane >> 3);
  int scol = ((lane & 7) ^ (lane >> 3)) * 8;

  uint32_t xm = (uint32_t)((r15 & 7) << 4);
  uint32_t offK0 = ((uint32_t)(g4 * 16)) ^ xm;
  uint32_t offK1 = ((uint32_t)(g4 * 16 + 64)) ^ xm;
  uint32_t aRd = asb + (uint32_t)((wr * 128 + r15) * 128);
  uint32_t bRd = bsb + (uint32_t)((wc * 64 + r15) * 128);

  f32x4 acc[8][4];
#pragma unroll
  for (int i = 0; i < 8; i++)
#pragma unroll
    for (int j = 0; j < 4; j++) acc[i][j] = (f32x4){0.f, 0.f, 0.f, 0.f};

  bf16x8 a0[8], a1[8], b0[4], b1[4];

#pragma unroll
  for (int q = 0; q < 4; q++) STAGE_(q, 0, 0);
  asm volatile("s_waitcnt vmcnt(0)" ::: "memory");
  BAR_();

  int NT = K >> 6;
  for (int kt = 0; kt < NT; ++kt) {
    int buf = kt & 1;
    bool pf = (kt + 1 < NT);
    if (pf) {
#pragma unroll
      for (int q = 0; q < 4; q++) STAGE_(q, kt + 1, buf ^ 1);
    }
    RDS_(a0, b0, 0, buf);
    RDS_(a1, b1, 1, buf);
    WLGN_(12);
    MFH_(a0, b0);
    WLGN_(0);
    MFH_(a1, b1);
    asm volatile("s_waitcnt vmcnt(0)" ::: "memory");
    BAR_();
  }

#pragma unroll
  for (int m = 0; m < 8; m++) {
    size_t row0 = (size_t)rowBase + wr * 128 + m * 16 + g4 * 4;
#pragma unroll
    for (int n = 0; n < 4; n++) {
      size_t col = (size_t)colBase + wc * 64 + n * 16 + r15;
      float bi = HASB ? bias[col] : 0.f;
#pragma unroll
      for (int qq = 0; qq < 4; qq++) {
        size_t row = row0 + qq;
        float v = acc[m][n][qq] + bi;
        if (HASRELU) v = fmaxf(v, 0.f);
        if (HASRES) v += resid[row * (size_t)N + col];
        if (OUTBF)
          ((bf16_t*)Cout)[row * (size_t)N + col] = (bf16_t)v;
        else
          ((float*)Cout)[row * (size_t)N + col] = v;
      }
    }
  }
}

// ---------------------------------------------------------------- launch
extern "C" void kernel_launch(void* const* d_in, const int* in_sizes, int n_in,
                              void* d_out, int out_size, void* d_ws, size_t ws_size,
                              hipStream_t stream) {
  (void)in_sizes; (void)n_in; (void)out_size; (void)ws_size;
  const int* idx = (const int*)d_in[0];
  const float* tok_emb = (const float*)d_in[1];
  const float* pos_emb = (const float*)d_in[2];
  const float* qkv_w = (const float*)d_in[3];
  const float* attn_out_w = (const float*)d_in[4];
  const float* attn_out_b = (const float*)d_in[5];
  const float* fc1_w = (const float*)d_in[6];
  const float* fc1_b = (const float*)d_in[7];
  const float* fc2_w = (const float*)d_in[8];
  const float* fc2_b = (const float*)d_in[9];
  const float* ln1_w = (const float*)d_in[10];
  const float* ln1_b = (const float*)d_in[11];
  const float* ln2_w = (const float*)d_in[12];
  const float* ln2_b = (const float*)d_in[13];
  const float* lnf_w = (const float*)d_in[14];
  const float* lnf_b = (const float*)d_in[15];
  const float* head_w = (const float*)d_in[16];
  float* out = (float*)d_out;

  char* wsp = (char*)d_ws;
  auto alloc = [&](size_t bytes) {
    char* p = wsp;
    wsp += (bytes + 255) & ~(size_t)255;
    return p;
  };
  float* x      = (float*)alloc((size_t)M_ * C_ * 4);
  bf16_t* hbuf  = (bf16_t*)alloc((size_t)M_ * C_ * 2);
  bf16_t* qhb   = (bf16_t*)alloc((size_t)3 * M_ * C_ * 2);   // q,k,v contiguous
  bf16_t* khb   = qhb + (size_t)M_ * C_;
  bf16_t* vhb   = khb + (size_t)M_ * C_;
  bf16_t* vTb   = (bf16_t*)alloc((size_t)M_ * C_ * 2);
  bf16_t* attnb = (bf16_t*)alloc((size_t)M_ * C_ * 2);
  bf16_t* midb  = (bf16_t*)alloc((size_t)M_ * 4 * C_ * 2);
  bf16_t* qkvwT = (bf16_t*)alloc((size_t)3 * C_ * C_ * 2);
  bf16_t* owT   = (bf16_t*)alloc((size_t)C_ * C_ * 2);
  bf16_t* fc1wT = (bf16_t*)alloc((size_t)4 * C_ * C_ * 2);
  bf16_t* fc2wT = (bf16_t*)alloc((size_t)4 * C_ * C_ * 2);
  bf16_t* headwT= (bf16_t*)alloc((size_t)C_ * V_ * 2);

  k_embed<<<M_, 256, 0, stream>>>(idx, tok_emb, pos_emb, x);
  k_transpose_bf16<<<dim3(V_ / 32, C_ / 32), 256, 0, stream>>>(head_w, headwT, C_, V_);

  for (int l = 0; l < L_; l++) {
    k_transpose_layer<<<12288, 256, 0, stream>>>(
        qkv_w + (size_t)l * C_ * 3 * C_, attn_out_w + (size_t)l * C_ * C_,
        fc1_w + (size_t)l * C_ * 4 * C_, fc2_w + (size_t)l * 4 * C_ * C_,
        qkvwT, owT, fc1wT, fc2wT);

    k_ln<<<M_, 256, 0, stream>>>(x, ln1_w + l * C_, ln1_b + l * C_, hbuf);
    k_gemm<2, 0, 0, 0><<<dim3(3 * C_ / 128, M_ / 128), 256, 0, stream>>>(
        hbuf, qkvwT, nullptr, nullptr, qhb, M_, 3 * C_, C_);
    k_vtrans<<<dim3(B_ * H_, T_ / 64), 256, 0, stream>>>(vhb, vTb);
    k_attn<<<dim3(B_ * H_, T_ / 64), 256, 0, stream>>>(qhb, khb, vTb, attnb);
    k_gemm<0, 1, 0, 1><<<dim3(C_ / 128, M_ / 128), 256, 0, stream>>>(
        attnb, owT, attn_out_b + l * C_, x, x, M_, C_, C_);

    k_ln<<<M_, 256, 0, stream>>>(x, ln2_w + l * C_, ln2_b + l * C_, hbuf);
    k_gemm<1, 1, 1, 0><<<dim3(4 * C_ / 128, M_ / 128), 256, 0, stream>>>(
        hbuf, fc1wT, fc1_b + (size_t)l * 4 * C_, nullptr, midb, M_, 4 * C_, C_);
    k_gemm<0, 1, 0, 1><<<dim3(C_ / 128, M_ / 128), 256, 0, stream>>>(
        midb, fc2wT, fc2_b + l * C_, x, x, M_, C_, 4 * C_);
  }

  k_ln<<<M_, 256, 0, stream>>>(x, lnf_w, lnf_b, hbuf);
  k_gemm256<0, 0, 0, 0><<<dim3((V_ / 256) * (M_ / 256)), 512, 0, stream>>>(
      hbuf, headwT, nullptr, nullptr, out, M_, V_, C_);
}